// Round 16
// baseline (463.288 us; speedup 1.0000x reference)
//
#include <hip/hip_runtime.h>
#include <hip/hip_bf16.h>

// BloodFlowSkinAnalyzer — f32 in/out (verified r5). Out layout (floats):
//   flow[4]@0, sync[4]@4, color[4*64*3]@8, masks[4,64,1,128,128]@776,
//   naturalness[4]@4195080, temporal[4,32,64]@4195084
// ws: colsum[4096][4] floats @0.
// conv1 on bf16 MFMA (HW-verified r7/r8); r16: conv2 on FP8 e4m3 MFMA
// (16x16x32 fp8_fp8 — same geometry, same swap/k-cancellation). h1 stored
// fp8 (LDS 25.6->15.3KB), bfrag 36->18 VGPR, launch_bounds(256,8) -> target
// 8 blocks/CU = 32 waves (+33% latency hiding; kernel is latency-bound).

typedef __attribute__((ext_vector_type(8))) short bf16x8;
typedef __attribute__((ext_vector_type(4))) float f32x4;

#define NAT_OFF  4195080
#define TF_OFF   4195084

__device__ __forceinline__ unsigned short f2bf(float f) {   // RNE f32->bf16
    unsigned u = __float_as_uint(f);
    u += 0x7FFFu + ((u >> 16) & 1u);
    return (unsigned short)(u >> 16);
}
__device__ __forceinline__ float bf2f(unsigned short u) {
    return __uint_as_float((unsigned)u << 16);
}
__device__ __forceinline__ unsigned pack_bf2(float lo, float hi) {
    __hip_bfloat162 h2 = __float22bfloat162_rn(make_float2(lo, hi));
    return *reinterpret_cast<unsigned*>(&h2);   // .x in low 16 bits
}

// Fused seg: conv1(3->32,k3,p1) bf16 MFMA + conv2(32->16,k3,p1) fp8 MFMA +
// conv3(16->1,k1)+sigmoid + masked sums. Block = 4 of 64 16x16 tiles.
__global__ __launch_bounds__(256, 8) void seg_kernel(
    const float* __restrict__ x,
    const float* __restrict__ w1f, const float* __restrict__ b1f,
    const float* __restrict__ w2f, const float* __restrict__ b2f,
    const float* __restrict__ w3f, const float* __restrict__ b3f,
    float* __restrict__ colsum, float* __restrict__ out)
{
    const int tid  = threadIdx.x;
    const int lane = tid & 63;
    const int wid  = tid >> 6;
    const int img  = blockIdx.x >> 4;        // b*64+t
    const int part = blockIdx.x & 15;        // 4 tiles per part

    __shared__ __align__(4)  unsigned short in_bs[2][1200]; // dbuf 3x20x20 bf16
    __shared__ __align__(16) unsigned char h1_s[10368];     // [(y*18+x)*32+oc] fp8
    __shared__ float red[4][4];

    const int ocl = lane & 15;   // free idx
    const int g   = lane >> 4;   // k-group (8 k's each)

    // ---- conv1 B-frags (k = ic*9+ky*3+kx, w1 native [oc][k]); k>=27 -> 0 ----
    bf16x8 c1b0, c1b1;
    int offB[8];                 // per-lane in_bs element offsets for A gather
#pragma unroll
    for (int e = 0; e < 8; ++e) {
        int k = g * 8 + e;
        if (k < 27) {
            int ic = k / 9, r2 = k - ic * 9, ky = r2 / 3, kx = r2 - ky * 3;
            offB[e] = ic * 400 + ky * 20 + kx;
            c1b0[e] = (short)f2bf(w1f[(2 * ocl)     * 27 + k]);
            c1b1[e] = (short)f2bf(w1f[(2 * ocl + 1) * 27 + k]);
        } else {
            offB[e] = 0;
            c1b0[e] = 0; c1b1[e] = 0;
        }
    }
    const float b1_e = b1f[2 * ocl], b1_o = b1f[2 * ocl + 1];

    // ---- conv2 W-frags as FP8 (MFMA A operand after swap): 9 x 8 fp8 ----
    long bfrag[9];
#pragma unroll
    for (int c = 0; c < 9; ++c) {
        float w[8];
#pragma unroll
        for (int e = 0; e < 8; ++e)
            w[e] = w2f[(ocl * 32 + g * 8 + e) * 9 + c];
        int lo = __builtin_amdgcn_cvt_pk_fp8_f32(w[0], w[1], 0, false);
        lo     = __builtin_amdgcn_cvt_pk_fp8_f32(w[2], w[3], lo, true);
        int hi = __builtin_amdgcn_cvt_pk_fp8_f32(w[4], w[5], 0, false);
        hi     = __builtin_amdgcn_cvt_pk_fp8_f32(w[6], w[7], hi, true);
        bfrag[c] = (long)(unsigned)lo | ((long)hi << 32);
    }
    // conv3 per-lane constants for oc = g*4+r (D rows after swap)
    float b2v[4], w3v[4];
#pragma unroll
    for (int r = 0; r < 4; ++r) { b2v[r] = b2f[g * 4 + r]; w3v[r] = w3f[g * 4 + r]; }
    const float b3v = b3f[0];

    const float* xin = x + (size_t)img * 3 * 16384;
    float s0 = 0.f, s1 = 0.f, s2 = 0.f, sm = 0.f;

    // ---- prologue: stage tile 0 into buffer 0 ----
    {
        const int tile0 = part * 4;
        const int r0 = (tile0 >> 3) * 16, c0 = (tile0 & 7) * 16;
        for (int idx = tid; idx < 1200; idx += 256) {
            int ic = idx / 400, rem = idx - ic * 400;
            int r = rem / 20, cc = rem - r * 20;
            int gr = r0 - 2 + r, gc = c0 - 2 + cc;
            float vv = 0.f;
            if ((unsigned)gr < 128u && (unsigned)gc < 128u)
                vv = xin[ic * 16384 + gr * 128 + gc];
            in_bs[0][idx] = f2bf(vv);
        }
    }
    __syncthreads();

    for (int tt = 0; tt < 4; ++tt) {
        const int cur = tt & 1;
        const unsigned short* inb = in_bs[cur];
        const int tile = part * 4 + tt;
        const int r0 = (tile >> 3) * 16, c0 = (tile & 7) * 16;
        const bool interior = (r0 >= 16 && r0 <= 96 && c0 >= 16 && c0 <= 96);

        // ---- issue next tile's loads NOW (latency hides under conv1+conv2).
        float nv[5];
        if (tt < 3) {
            const int tn = tile + 1;
            const int r0n = (tn >> 3) * 16, c0n = (tn & 7) * 16;
#pragma unroll
            for (int s = 0; s < 5; ++s) {
                int idx = tid + 256 * s;
                nv[s] = 0.f;
                if (idx < 1200) {
                    int ic = idx / 400, rem = idx - ic * 400;
                    int r = rem / 20, cc = rem - r * 20;
                    int gr = r0n - 2 + r, gc = c0n - 2 + cc;
                    if ((unsigned)gr < 128u && (unsigned)gc < 128u)
                        nv[s] = xin[ic * 16384 + gr * 128 + gc];
                }
            }
        }

        // ---- conv1 MFMA: 21 groups of 16 positions over 4 waves ----
        for (int grp = wid; grp < 21; grp += 4) {
            int pos = grp * 16 + ocl;                 // A row
            int hy = pos / 18, hx = pos - hy * 18;
            int base = hy * 20 + hx;
            base = base > 357 ? 357 : base;           // clamp tail-group lanes
            bf16x8 afrag;
#pragma unroll
            for (int e = 0; e < 8; ++e)
                afrag[e] = (short)inb[base + offB[e]];
            f32x4 d0 = {0.f, 0.f, 0.f, 0.f}, d1 = {0.f, 0.f, 0.f, 0.f};
            d0 = __builtin_amdgcn_mfma_f32_16x16x32_bf16(afrag, c1b0, d0, 0, 0, 0);
            d1 = __builtin_amdgcn_mfma_f32_16x16x32_bf16(afrag, c1b1, d1, 0, 0, 0);
            int p0 = grp * 16 + g * 4;
            if (interior) {
#pragma unroll
                for (int r = 0; r < 4; ++r) {
                    int p2 = p0 + r;
                    if (p2 < 324) {
                        int pk = __builtin_amdgcn_cvt_pk_fp8_f32(
                            fmaxf(d0[r] + b1_e, 0.f), fmaxf(d1[r] + b1_o, 0.f), 0, false);
                        *reinterpret_cast<unsigned short*>(&h1_s[p2 * 32 + 2 * ocl]) =
                            (unsigned short)pk;
                    }
                }
            } else {
                int hy2 = p0 / 18, hx2 = p0 - hy2 * 18;
#pragma unroll
                for (int r = 0; r < 4; ++r) {
                    int p2 = p0 + r;
                    if (p2 < 324) {
                        bool valid = ((unsigned)(r0 - 1 + hy2) < 128u) &&
                                     ((unsigned)(c0 - 1 + hx2) < 128u);
                        float he = valid ? fmaxf(d0[r] + b1_e, 0.f) : 0.f;
                        float ho = valid ? fmaxf(d1[r] + b1_o, 0.f) : 0.f;
                        int pk = __builtin_amdgcn_cvt_pk_fp8_f32(he, ho, 0, false);
                        *reinterpret_cast<unsigned short*>(&h1_s[p2 * 32 + 2 * ocl]) =
                            (unsigned short)pk;
                    }
                    ++hx2;
                    if (hx2 == 18) { hx2 = 0; ++hy2; }
                }
            }
        }
        __syncthreads();

        // ---- conv2 FP8 MFMA: swapped operands (A=w2 fp8, B=h1 fp8).
        //      Row-reuse: 18 ds_read_b64; per-q accumulation order fixed.
        const unsigned char* hb = &h1_s[((wid * 4) * 18 + ocl) * 32 + g * 8];
        f32x4 acc4[4];
#pragma unroll
        for (int q = 0; q < 4; ++q) acc4[q] = (f32x4){0.f, 0.f, 0.f, 0.f};
#pragma unroll
        for (int rp = 0; rp < 6; ++rp) {
            long fr0 = *reinterpret_cast<const long*>(hb + (rp * 18 + 0) * 32);
            long fr1 = *reinterpret_cast<const long*>(hb + (rp * 18 + 1) * 32);
            long fr2 = *reinterpret_cast<const long*>(hb + (rp * 18 + 2) * 32);
#pragma unroll
            for (int ky = 0; ky < 3; ++ky) {
                const int q = rp - ky;
                if (q >= 0 && q < 4) {
                    acc4[q] = __builtin_amdgcn_mfma_f32_16x16x32_fp8_fp8(
                        bfrag[ky * 3 + 0], fr0, acc4[q], 0, 0, 0);
                    acc4[q] = __builtin_amdgcn_mfma_f32_16x16x32_fp8_fp8(
                        bfrag[ky * 3 + 1], fr1, acc4[q], 0, 0, 0);
                    acc4[q] = __builtin_amdgcn_mfma_f32_16x16x32_fp8_fp8(
                        bfrag[ky * 3 + 2], fr2, acc4[q], 0, 0, 0);
                }
            }
        }
        // conv3: lane holds P[oc=g*4+r][x=ocl]; 4 in-lane FMA + 2 shfl
#pragma unroll
        for (int q = 0; q < 4; ++q) {
            const int s = wid * 4 + q;
            float part3 = 0.f;
#pragma unroll
            for (int r = 0; r < 4; ++r)
                part3 = fmaf(fmaxf(acc4[q][r] + b2v[r], 0.f), w3v[r], part3);
            part3 += __shfl_xor(part3, 16);
            part3 += __shfl_xor(part3, 32);
            if (lane < 16) {
                int xw = lane;
                float msk = 1.f / (1.f + __expf(-(part3 + b3v)));
                out[776 + (size_t)img * 16384 + (size_t)(r0 + s) * 128 + (c0 + xw)] = msk;
                float f0  = bf2f(inb[      (s + 2) * 20 + (xw + 2)]);
                float f1v = bf2f(inb[400 + (s + 2) * 20 + (xw + 2)]);
                float f2v = bf2f(inb[800 + (s + 2) * 20 + (xw + 2)]);
                s0 = fmaf(msk, f0, s0);
                s1 = fmaf(msk, f1v, s1);
                s2 = fmaf(msk, f2v, s2);
                sm += msk;
            }
        }

        // ---- write next tile's halo into the other buffer ----
        if (tt < 3) {
#pragma unroll
            for (int s = 0; s < 5; ++s) {
                int idx = tid + 256 * s;
                if (idx < 1200) in_bs[cur ^ 1][idx] = f2bf(nv[s]);
            }
        }
        __syncthreads();
    }

    // ---- block reduction of the 4 sums ----
#pragma unroll
    for (int off = 32; off > 0; off >>= 1) {
        s0 += __shfl_down(s0, off);
        s1 += __shfl_down(s1, off);
        s2 += __shfl_down(s2, off);
        sm += __shfl_down(sm, off);
    }
    if (lane == 0) { red[wid][0] = s0; red[wid][1] = s1; red[wid][2] = s2; red[wid][3] = sm; }
    __syncthreads();
    if (tid < 4) {
        float s = red[0][tid] + red[1][tid] + red[2][tid] + red[3][tid];
        colsum[(size_t)blockIdx.x * 4 + tid] = s;   // [img][part][4]
    }
}

// Tail: 1024 threads; ta2/ta3 vectorized (b128 + lane-shfl conv halo).
__global__ __launch_bounds__(1024) void tail_kernel(
    const float* __restrict__ colsum,
    const float* __restrict__ cw1, const float* __restrict__ cb1,
    const float* __restrict__ cw2, const float* __restrict__ cb2,
    const float* __restrict__ cw3, const float* __restrict__ cb3,
    const float* __restrict__ tw1, const float* __restrict__ tb1,
    const float* __restrict__ tw2, const float* __restrict__ tb2,
    const float* __restrict__ tw3, const float* __restrict__ tb3,
    const float* __restrict__ fw1, const float* __restrict__ fb1,
    const float* __restrict__ fw2, const float* __restrict__ fb2,
    const float* __restrict__ fw3, const float* __restrict__ fb3,
    float* __restrict__ out)
{
    const int b = blockIdx.x, tid = threadIdx.x;
    __shared__ float tmp[64][4];
    __shared__ float cs_s[3 * 64];
    __shared__ float e3s[3 * 64];
    __shared__ __align__(16) float f1[32 * 64];
    __shared__ __align__(16) float f2[64 * 64];
    __shared__ __align__(16) float tf[32 * 64];
    __shared__ float pooled[32], g1[64], g2[32], sca[8];

    if (tid < 256) {
        int t = tid >> 2, slot = tid & 3;
        const float* pp = colsum + (size_t)((b * 64 + t) * 16) * 4 + slot;
        float s = 0.f;
#pragma unroll
        for (int p = 0; p < 16; ++p) s += pp[p * 4];
        tmp[t][slot] = s;
    }
    __syncthreads();
    if (tid < 192) {
        int c = tid >> 6, t = tid & 63;
        float v = tmp[t][c] / (tmp[t][3] + 1e-8f);
        cs_s[tid] = v;
        out[8 + (b * 64 + t) * 3 + c] = v;
    }
    __syncthreads();

    if (tid < 64) {
        int t = tid;
        float c0v = cs_s[t], c1v = cs_s[64 + t], c2v = cs_s[128 + t];
        float e1[16];
#pragma unroll
        for (int o = 0; o < 16; ++o)
            e1[o] = fmaxf(cb1[o] + cw1[o * 3 + 0] * c0v + cw1[o * 3 + 1] * c1v
                                 + cw1[o * 3 + 2] * c2v, 0.f);
        float e2[8];
#pragma unroll
        for (int o = 0; o < 8; ++o) {
            float a = cb2[o];
#pragma unroll
            for (int i2 = 0; i2 < 16; ++i2) a += cw2[o * 16 + i2] * e1[i2];
            e2[o] = fmaxf(a, 0.f);
        }
#pragma unroll
        for (int o = 0; o < 3; ++o) {
            float a = cb3[o];
#pragma unroll
            for (int i2 = 0; i2 < 8; ++i2) a += cw3[o * 8 + i2] * e2[i2];
            e3s[o * 64 + t] = a;   // no relu on last ct conv
        }
    }
    __syncthreads();

    // ta1: 3->32 k3 p1
    {
        int o = tid >> 6, t = tid & 63;
#pragma unroll
        for (int h = 0; h < 2; ++h) {
            int oo = o + 16 * h;
            float a = tb1[oo];
#pragma unroll
            for (int ic = 0; ic < 3; ++ic)
#pragma unroll
                for (int k = 0; k < 3; ++k) {
                    int ttk = t + k - 1;
                    if ((unsigned)ttk < 64u)
                        a += e3s[ic * 64 + ttk] * tw1[(oo * 3 + ic) * 3 + k];
                }
            f1[oo * 64 + t] = fmaxf(a, 0.f);
        }
    }
    __syncthreads();

    // ta2: 32->64 k3 p1 — thread (oo=tid>>4, t4=tid&15) computes t=4t4..4t4+3
    {
        int oo = tid >> 4, t4 = tid & 15;
        float a0 = tb2[oo], a1 = a0, a2 = a0, a3 = a0;
        for (int ic = 0; ic < 32; ++ic) {
            f32x4 c = *reinterpret_cast<const f32x4*>(&f1[ic * 64 + t4 * 4]);
            float pm = __shfl_up(c[3], 1);
            float pp = __shfl_down(c[0], 1);
            if (t4 == 0)  pm = 0.f;          // t-1 < 0 pad
            if (t4 == 15) pp = 0.f;          // t+1 > 63 pad
            const float* wp = tw2 + (oo * 32 + ic) * 3;
            float w0 = wp[0], w1 = wp[1], w2 = wp[2];
            a0 = fmaf(w0, pm,   fmaf(w1, c[0], fmaf(w2, c[1], a0)));
            a1 = fmaf(w0, c[0], fmaf(w1, c[1], fmaf(w2, c[2], a1)));
            a2 = fmaf(w0, c[1], fmaf(w1, c[2], fmaf(w2, c[3], a2)));
            a3 = fmaf(w0, c[2], fmaf(w1, c[3], fmaf(w2, pp,   a3)));
        }
        f32x4 r = {fmaxf(a0, 0.f), fmaxf(a1, 0.f), fmaxf(a2, 0.f), fmaxf(a3, 0.f)};
        *reinterpret_cast<f32x4*>(&f2[oo * 64 + t4 * 4]) = r;
    }
    __syncthreads();

    // ta3: 64->32 k3 p1 (+ temporal_features out), threads 0..511
    if (tid < 512) {
        int oo = tid >> 4, t4 = tid & 15;
        float a0 = tb3[oo], a1 = a0, a2 = a0, a3 = a0;
        for (int ic = 0; ic < 64; ++ic) {
            f32x4 c = *reinterpret_cast<const f32x4*>(&f2[ic * 64 + t4 * 4]);
            float pm = __shfl_up(c[3], 1);
            float pp = __shfl_down(c[0], 1);
            if (t4 == 0)  pm = 0.f;
            if (t4 == 15) pp = 0.f;
            const float* wp = tw3 + (oo * 64 + ic) * 3;
            float w0 = wp[0], w1 = wp[1], w2 = wp[2];
            a0 = fmaf(w0, pm,   fmaf(w1, c[0], fmaf(w2, c[1], a0)));
            a1 = fmaf(w0, c[0], fmaf(w1, c[1], fmaf(w2, c[2], a1)));
            a2 = fmaf(w0, c[1], fmaf(w1, c[2], fmaf(w2, c[3], a2)));
            a3 = fmaf(w0, c[2], fmaf(w1, c[3], fmaf(w2, pp,   a3)));
        }
        f32x4 r = {fmaxf(a0, 0.f), fmaxf(a1, 0.f), fmaxf(a2, 0.f), fmaxf(a3, 0.f)};
        *reinterpret_cast<f32x4*>(&tf[oo * 64 + t4 * 4]) = r;
        *reinterpret_cast<f32x4*>(&out[TF_OFF + (b * 32 + oo) * 64 + t4 * 4]) = r;
    }
    __syncthreads();

    if (tid < 32) {
        float s = 0.f;
#pragma unroll
        for (int t4 = 0; t4 < 16; ++t4) {
            f32x4 c = *reinterpret_cast<const f32x4*>(&tf[tid * 64 + t4 * 4]);
            s += c[0] + c[1] + c[2] + c[3];
        }
        pooled[tid] = s * (1.f / 64.f);
    }
    __syncthreads();

    if (tid < 64) {
        float a = fb1[tid];
#pragma unroll
        for (int i2 = 0; i2 < 32; ++i2) a += pooled[i2] * fw1[tid * 32 + i2];
        g1[tid] = fmaxf(a, 0.f);
    }
    __syncthreads();
    if (tid < 32) {
        float a = fb2[tid];
        for (int i2 = 0; i2 < 64; ++i2) a += g1[i2] * fw2[tid * 64 + i2];
        g2[tid] = fmaxf(a, 0.f);
    }
    __syncthreads();
    if (tid == 0) {
        float a = fb3[0];
        for (int i2 = 0; i2 < 32; ++i2) a += g2[i2] * fw3[i2];
        float flow = 1.f / (1.f + expf(-a));
        sca[0] = flow;
        out[b] = flow;
    }
    if (tid >= 4 && tid < 7) {
        int c = tid - 4;
        float mu = 0.f;
        for (int t = 0; t < 64; ++t) mu += cs_s[c * 64 + t];
        mu *= (1.f / 64.f);
        float v = 0.f;
        for (int t = 0; t < 64; ++t) { float d = cs_s[c * 64 + t] - mu; v += d * d; }
        sca[1 + c] = sqrtf(v / 63.f);
    }
    __syncthreads();
    if (tid == 0) {
        float s0 = sca[1], s1 = sca[2], s2 = sca[3];
        float mu = (s0 + s1 + s2) * (1.f / 3.f);
        float var = ((s0 - mu) * (s0 - mu) + (s1 - mu) * (s1 - mu) + (s2 - mu) * (s2 - mu)) * 0.5f;
        float sy = 1.f / (1.f + expf(var));     // sigmoid(-var)
        out[4 + b] = sy;
        out[NAT_OFF + b] = (sca[0] + sy) * 0.5f;
    }
}

extern "C" void kernel_launch(void* const* d_in, const int* in_sizes, int n_in,
                              void* d_out, int out_size, void* d_ws, size_t ws_size,
                              hipStream_t stream)
{
    float* wsf = (float*)d_ws;
    float* out = (float*)d_out;

    seg_kernel<<<dim3(4096), 256, 0, stream>>>((const float*)d_in[0],
        (const float*)d_in[1], (const float*)d_in[2],
        (const float*)d_in[3], (const float*)d_in[4],
        (const float*)d_in[5], (const float*)d_in[6],
        wsf, out);

    tail_kernel<<<dim3(4), 1024, 0, stream>>>(wsf,
        (const float*)d_in[7],  (const float*)d_in[8],
        (const float*)d_in[9],  (const float*)d_in[10],
        (const float*)d_in[11], (const float*)d_in[12],
        (const float*)d_in[13], (const float*)d_in[14],
        (const float*)d_in[15], (const float*)d_in[16],
        (const float*)d_in[17], (const float*)d_in[18],
        (const float*)d_in[19], (const float*)d_in[20],
        (const float*)d_in[21], (const float*)d_in[22],
        (const float*)d_in[23], (const float*)d_in[24],
        out);
}

// Round 17
// 294.714 us; speedup vs baseline: 1.5720x; 1.5720x over previous
//
#include <hip/hip_runtime.h>
#include <hip/hip_bf16.h>

// BloodFlowSkinAnalyzer — f32 in/out (verified r5). Out layout (floats):
//   flow[4]@0, sync[4]@4, color[4*64*3]@8, masks[4,64,1,128,128]@776,
//   naturalness[4]@4195080, temporal[4,32,64]@4195084
// ws: colsum[4096][4] floats @0.
// conv1 bf16 MFMA (HW-verified r7/r8); conv2 FP8 e4m3 MFMA (numerics
// verified r16: absmax 0.0039). r17: launch_bounds (256,8)->(256,6) — r16's
// bound forced VGPR=32 and spilled (FETCH 45->736MB). Cap 512/6=85 fits the
// kernel's natural ~84 -> no spill, 6 blocks/CU (+20% waves vs r14).

typedef __attribute__((ext_vector_type(8))) short bf16x8;
typedef __attribute__((ext_vector_type(4))) float f32x4;

#define NAT_OFF  4195080
#define TF_OFF   4195084

__device__ __forceinline__ unsigned short f2bf(float f) {   // RNE f32->bf16
    unsigned u = __float_as_uint(f);
    u += 0x7FFFu + ((u >> 16) & 1u);
    return (unsigned short)(u >> 16);
}
__device__ __forceinline__ float bf2f(unsigned short u) {
    return __uint_as_float((unsigned)u << 16);
}

// Fused seg: conv1(3->32,k3,p1) bf16 MFMA + conv2(32->16,k3,p1) fp8 MFMA +
// conv3(16->1,k1)+sigmoid + masked sums. Block = 4 of 64 16x16 tiles.
__global__ __launch_bounds__(256, 6) void seg_kernel(
    const float* __restrict__ x,
    const float* __restrict__ w1f, const float* __restrict__ b1f,
    const float* __restrict__ w2f, const float* __restrict__ b2f,
    const float* __restrict__ w3f, const float* __restrict__ b3f,
    float* __restrict__ colsum, float* __restrict__ out)
{
    const int tid  = threadIdx.x;
    const int lane = tid & 63;
    const int wid  = tid >> 6;
    const int img  = blockIdx.x >> 4;        // b*64+t
    const int part = blockIdx.x & 15;        // 4 tiles per part

    __shared__ __align__(4)  unsigned short in_bs[2][1200]; // dbuf 3x20x20 bf16
    __shared__ __align__(16) unsigned char h1_s[10368];     // [(y*18+x)*32+oc] fp8
    __shared__ float red[4][4];

    const int ocl = lane & 15;   // free idx
    const int g   = lane >> 4;   // k-group (8 k's each)

    // ---- conv1 B-frags (k = ic*9+ky*3+kx, w1 native [oc][k]); k>=27 -> 0 ----
    bf16x8 c1b0, c1b1;
    int offB[8];                 // per-lane in_bs element offsets for A gather
#pragma unroll
    for (int e = 0; e < 8; ++e) {
        int k = g * 8 + e;
        if (k < 27) {
            int ic = k / 9, r2 = k - ic * 9, ky = r2 / 3, kx = r2 - ky * 3;
            offB[e] = ic * 400 + ky * 20 + kx;
            c1b0[e] = (short)f2bf(w1f[(2 * ocl)     * 27 + k]);
            c1b1[e] = (short)f2bf(w1f[(2 * ocl + 1) * 27 + k]);
        } else {
            offB[e] = 0;
            c1b0[e] = 0; c1b1[e] = 0;
        }
    }
    const float b1_e = b1f[2 * ocl], b1_o = b1f[2 * ocl + 1];

    // ---- conv2 W-frags as FP8 (MFMA A operand after swap): 9 x 8 fp8 ----
    long bfrag[9];
#pragma unroll
    for (int c = 0; c < 9; ++c) {
        float w[8];
#pragma unroll
        for (int e = 0; e < 8; ++e)
            w[e] = w2f[(ocl * 32 + g * 8 + e) * 9 + c];
        int lo = __builtin_amdgcn_cvt_pk_fp8_f32(w[0], w[1], 0, false);
        lo     = __builtin_amdgcn_cvt_pk_fp8_f32(w[2], w[3], lo, true);
        int hi = __builtin_amdgcn_cvt_pk_fp8_f32(w[4], w[5], 0, false);
        hi     = __builtin_amdgcn_cvt_pk_fp8_f32(w[6], w[7], hi, true);
        bfrag[c] = (long)(unsigned)lo | ((long)hi << 32);
    }
    // conv3 per-lane constants for oc = g*4+r (D rows after swap)
    float b2v[4], w3v[4];
#pragma unroll
    for (int r = 0; r < 4; ++r) { b2v[r] = b2f[g * 4 + r]; w3v[r] = w3f[g * 4 + r]; }
    const float b3v = b3f[0];

    const float* xin = x + (size_t)img * 3 * 16384;
    float s0 = 0.f, s1 = 0.f, s2 = 0.f, sm = 0.f;

    // ---- prologue: stage tile 0 into buffer 0 ----
    {
        const int tile0 = part * 4;
        const int r0 = (tile0 >> 3) * 16, c0 = (tile0 & 7) * 16;
        for (int idx = tid; idx < 1200; idx += 256) {
            int ic = idx / 400, rem = idx - ic * 400;
            int r = rem / 20, cc = rem - r * 20;
            int gr = r0 - 2 + r, gc = c0 - 2 + cc;
            float vv = 0.f;
            if ((unsigned)gr < 128u && (unsigned)gc < 128u)
                vv = xin[ic * 16384 + gr * 128 + gc];
            in_bs[0][idx] = f2bf(vv);
        }
    }
    __syncthreads();

    for (int tt = 0; tt < 4; ++tt) {
        const int cur = tt & 1;
        const unsigned short* inb = in_bs[cur];
        const int tile = part * 4 + tt;
        const int r0 = (tile >> 3) * 16, c0 = (tile & 7) * 16;
        const bool interior = (r0 >= 16 && r0 <= 96 && c0 >= 16 && c0 <= 96);

        // ---- issue next tile's loads NOW (latency hides under conv1+conv2).
        float nv[5];
        if (tt < 3) {
            const int tn = tile + 1;
            const int r0n = (tn >> 3) * 16, c0n = (tn & 7) * 16;
#pragma unroll
            for (int s = 0; s < 5; ++s) {
                int idx = tid + 256 * s;
                nv[s] = 0.f;
                if (idx < 1200) {
                    int ic = idx / 400, rem = idx - ic * 400;
                    int r = rem / 20, cc = rem - r * 20;
                    int gr = r0n - 2 + r, gc = c0n - 2 + cc;
                    if ((unsigned)gr < 128u && (unsigned)gc < 128u)
                        nv[s] = xin[ic * 16384 + gr * 128 + gc];
                }
            }
        }

        // ---- conv1 MFMA: 21 groups of 16 positions over 4 waves ----
        for (int grp = wid; grp < 21; grp += 4) {
            int pos = grp * 16 + ocl;                 // A row
            int hy = pos / 18, hx = pos - hy * 18;
            int base = hy * 20 + hx;
            base = base > 357 ? 357 : base;           // clamp tail-group lanes
            bf16x8 afrag;
#pragma unroll
            for (int e = 0; e < 8; ++e)
                afrag[e] = (short)inb[base + offB[e]];
            f32x4 d0 = {0.f, 0.f, 0.f, 0.f}, d1 = {0.f, 0.f, 0.f, 0.f};
            d0 = __builtin_amdgcn_mfma_f32_16x16x32_bf16(afrag, c1b0, d0, 0, 0, 0);
            d1 = __builtin_amdgcn_mfma_f32_16x16x32_bf16(afrag, c1b1, d1, 0, 0, 0);
            int p0 = grp * 16 + g * 4;
            if (interior) {
#pragma unroll
                for (int r = 0; r < 4; ++r) {
                    int p2 = p0 + r;
                    if (p2 < 324) {
                        int pk = __builtin_amdgcn_cvt_pk_fp8_f32(
                            fmaxf(d0[r] + b1_e, 0.f), fmaxf(d1[r] + b1_o, 0.f), 0, false);
                        *reinterpret_cast<unsigned short*>(&h1_s[p2 * 32 + 2 * ocl]) =
                            (unsigned short)pk;
                    }
                }
            } else {
                int hy2 = p0 / 18, hx2 = p0 - hy2 * 18;
#pragma unroll
                for (int r = 0; r < 4; ++r) {
                    int p2 = p0 + r;
                    if (p2 < 324) {
                        bool valid = ((unsigned)(r0 - 1 + hy2) < 128u) &&
                                     ((unsigned)(c0 - 1 + hx2) < 128u);
                        float he = valid ? fmaxf(d0[r] + b1_e, 0.f) : 0.f;
                        float ho = valid ? fmaxf(d1[r] + b1_o, 0.f) : 0.f;
                        int pk = __builtin_amdgcn_cvt_pk_fp8_f32(he, ho, 0, false);
                        *reinterpret_cast<unsigned short*>(&h1_s[p2 * 32 + 2 * ocl]) =
                            (unsigned short)pk;
                    }
                    ++hx2;
                    if (hx2 == 18) { hx2 = 0; ++hy2; }
                }
            }
        }
        __syncthreads();

        // ---- conv2 FP8 MFMA: swapped operands (A=w2 fp8, B=h1 fp8).
        //      Row-reuse: 18 ds_read_b64; per-q accumulation order fixed.
        const unsigned char* hb = &h1_s[((wid * 4) * 18 + ocl) * 32 + g * 8];
        f32x4 acc4[4];
#pragma unroll
        for (int q = 0; q < 4; ++q) acc4[q] = (f32x4){0.f, 0.f, 0.f, 0.f};
#pragma unroll
        for (int rp = 0; rp < 6; ++rp) {
            long fr0 = *reinterpret_cast<const long*>(hb + (rp * 18 + 0) * 32);
            long fr1 = *reinterpret_cast<const long*>(hb + (rp * 18 + 1) * 32);
            long fr2 = *reinterpret_cast<const long*>(hb + (rp * 18 + 2) * 32);
#pragma unroll
            for (int ky = 0; ky < 3; ++ky) {
                const int q = rp - ky;
                if (q >= 0 && q < 4) {
                    acc4[q] = __builtin_amdgcn_mfma_f32_16x16x32_fp8_fp8(
                        bfrag[ky * 3 + 0], fr0, acc4[q], 0, 0, 0);
                    acc4[q] = __builtin_amdgcn_mfma_f32_16x16x32_fp8_fp8(
                        bfrag[ky * 3 + 1], fr1, acc4[q], 0, 0, 0);
                    acc4[q] = __builtin_amdgcn_mfma_f32_16x16x32_fp8_fp8(
                        bfrag[ky * 3 + 2], fr2, acc4[q], 0, 0, 0);
                }
            }
        }
        // conv3: lane holds P[oc=g*4+r][x=ocl]; 4 in-lane FMA + 2 shfl
#pragma unroll
        for (int q = 0; q < 4; ++q) {
            const int s = wid * 4 + q;
            float part3 = 0.f;
#pragma unroll
            for (int r = 0; r < 4; ++r)
                part3 = fmaf(fmaxf(acc4[q][r] + b2v[r], 0.f), w3v[r], part3);
            part3 += __shfl_xor(part3, 16);
            part3 += __shfl_xor(part3, 32);
            if (lane < 16) {
                int xw = lane;
                float msk = 1.f / (1.f + __expf(-(part3 + b3v)));
                out[776 + (size_t)img * 16384 + (size_t)(r0 + s) * 128 + (c0 + xw)] = msk;
                float f0  = bf2f(inb[      (s + 2) * 20 + (xw + 2)]);
                float f1v = bf2f(inb[400 + (s + 2) * 20 + (xw + 2)]);
                float f2v = bf2f(inb[800 + (s + 2) * 20 + (xw + 2)]);
                s0 = fmaf(msk, f0, s0);
                s1 = fmaf(msk, f1v, s1);
                s2 = fmaf(msk, f2v, s2);
                sm += msk;
            }
        }

        // ---- write next tile's halo into the other buffer ----
        if (tt < 3) {
#pragma unroll
            for (int s = 0; s < 5; ++s) {
                int idx = tid + 256 * s;
                if (idx < 1200) in_bs[cur ^ 1][idx] = f2bf(nv[s]);
            }
        }
        __syncthreads();
    }

    // ---- block reduction of the 4 sums ----
#pragma unroll
    for (int off = 32; off > 0; off >>= 1) {
        s0 += __shfl_down(s0, off);
        s1 += __shfl_down(s1, off);
        s2 += __shfl_down(s2, off);
        sm += __shfl_down(sm, off);
    }
    if (lane == 0) { red[wid][0] = s0; red[wid][1] = s1; red[wid][2] = s2; red[wid][3] = sm; }
    __syncthreads();
    if (tid < 4) {
        float s = red[0][tid] + red[1][tid] + red[2][tid] + red[3][tid];
        colsum[(size_t)blockIdx.x * 4 + tid] = s;   // [img][part][4]
    }
}

// Tail: 1024 threads; ta2/ta3 vectorized (b128 + lane-shfl conv halo).
__global__ __launch_bounds__(1024) void tail_kernel(
    const float* __restrict__ colsum,
    const float* __restrict__ cw1, const float* __restrict__ cb1,
    const float* __restrict__ cw2, const float* __restrict__ cb2,
    const float* __restrict__ cw3, const float* __restrict__ cb3,
    const float* __restrict__ tw1, const float* __restrict__ tb1,
    const float* __restrict__ tw2, const float* __restrict__ tb2,
    const float* __restrict__ tw3, const float* __restrict__ tb3,
    const float* __restrict__ fw1, const float* __restrict__ fb1,
    const float* __restrict__ fw2, const float* __restrict__ fb2,
    const float* __restrict__ fw3, const float* __restrict__ fb3,
    float* __restrict__ out)
{
    const int b = blockIdx.x, tid = threadIdx.x;
    __shared__ float tmp[64][4];
    __shared__ float cs_s[3 * 64];
    __shared__ float e3s[3 * 64];
    __shared__ __align__(16) float f1[32 * 64];
    __shared__ __align__(16) float f2[64 * 64];
    __shared__ __align__(16) float tf[32 * 64];
    __shared__ float pooled[32], g1[64], g2[32], sca[8];

    if (tid < 256) {
        int t = tid >> 2, slot = tid & 3;
        const float* pp = colsum + (size_t)((b * 64 + t) * 16) * 4 + slot;
        float s = 0.f;
#pragma unroll
        for (int p = 0; p < 16; ++p) s += pp[p * 4];
        tmp[t][slot] = s;
    }
    __syncthreads();
    if (tid < 192) {
        int c = tid >> 6, t = tid & 63;
        float v = tmp[t][c] / (tmp[t][3] + 1e-8f);
        cs_s[tid] = v;
        out[8 + (b * 64 + t) * 3 + c] = v;
    }
    __syncthreads();

    if (tid < 64) {
        int t = tid;
        float c0v = cs_s[t], c1v = cs_s[64 + t], c2v = cs_s[128 + t];
        float e1[16];
#pragma unroll
        for (int o = 0; o < 16; ++o)
            e1[o] = fmaxf(cb1[o] + cw1[o * 3 + 0] * c0v + cw1[o * 3 + 1] * c1v
                                 + cw1[o * 3 + 2] * c2v, 0.f);
        float e2[8];
#pragma unroll
        for (int o = 0; o < 8; ++o) {
            float a = cb2[o];
#pragma unroll
            for (int i2 = 0; i2 < 16; ++i2) a += cw2[o * 16 + i2] * e1[i2];
            e2[o] = fmaxf(a, 0.f);
        }
#pragma unroll
        for (int o = 0; o < 3; ++o) {
            float a = cb3[o];
#pragma unroll
            for (int i2 = 0; i2 < 8; ++i2) a += cw3[o * 8 + i2] * e2[i2];
            e3s[o * 64 + t] = a;   // no relu on last ct conv
        }
    }
    __syncthreads();

    // ta1: 3->32 k3 p1
    {
        int o = tid >> 6, t = tid & 63;
#pragma unroll
        for (int h = 0; h < 2; ++h) {
            int oo = o + 16 * h;
            float a = tb1[oo];
#pragma unroll
            for (int ic = 0; ic < 3; ++ic)
#pragma unroll
                for (int k = 0; k < 3; ++k) {
                    int ttk = t + k - 1;
                    if ((unsigned)ttk < 64u)
                        a += e3s[ic * 64 + ttk] * tw1[(oo * 3 + ic) * 3 + k];
                }
            f1[oo * 64 + t] = fmaxf(a, 0.f);
        }
    }
    __syncthreads();

    // ta2: 32->64 k3 p1 — thread (oo=tid>>4, t4=tid&15) computes t=4t4..4t4+3
    {
        int oo = tid >> 4, t4 = tid & 15;
        float a0 = tb2[oo], a1 = a0, a2 = a0, a3 = a0;
        for (int ic = 0; ic < 32; ++ic) {
            f32x4 c = *reinterpret_cast<const f32x4*>(&f1[ic * 64 + t4 * 4]);
            float pm = __shfl_up(c[3], 1);
            float pp = __shfl_down(c[0], 1);
            if (t4 == 0)  pm = 0.f;          // t-1 < 0 pad
            if (t4 == 15) pp = 0.f;          // t+1 > 63 pad
            const float* wp = tw2 + (oo * 32 + ic) * 3;
            float w0 = wp[0], w1 = wp[1], w2 = wp[2];
            a0 = fmaf(w0, pm,   fmaf(w1, c[0], fmaf(w2, c[1], a0)));
            a1 = fmaf(w0, c[0], fmaf(w1, c[1], fmaf(w2, c[2], a1)));
            a2 = fmaf(w0, c[1], fmaf(w1, c[2], fmaf(w2, c[3], a2)));
            a3 = fmaf(w0, c[2], fmaf(w1, c[3], fmaf(w2, pp,   a3)));
        }
        f32x4 r = {fmaxf(a0, 0.f), fmaxf(a1, 0.f), fmaxf(a2, 0.f), fmaxf(a3, 0.f)};
        *reinterpret_cast<f32x4*>(&f2[oo * 64 + t4 * 4]) = r;
    }
    __syncthreads();

    // ta3: 64->32 k3 p1 (+ temporal_features out), threads 0..511
    if (tid < 512) {
        int oo = tid >> 4, t4 = tid & 15;
        float a0 = tb3[oo], a1 = a0, a2 = a0, a3 = a0;
        for (int ic = 0; ic < 64; ++ic) {
            f32x4 c = *reinterpret_cast<const f32x4*>(&f2[ic * 64 + t4 * 4]);
            float pm = __shfl_up(c[3], 1);
            float pp = __shfl_down(c[0], 1);
            if (t4 == 0)  pm = 0.f;
            if (t4 == 15) pp = 0.f;
            const float* wp = tw3 + (oo * 64 + ic) * 3;
            float w0 = wp[0], w1 = wp[1], w2 = wp[2];
            a0 = fmaf(w0, pm,   fmaf(w1, c[0], fmaf(w2, c[1], a0)));
            a1 = fmaf(w0, c[0], fmaf(w1, c[1], fmaf(w2, c[2], a1)));
            a2 = fmaf(w0, c[1], fmaf(w1, c[2], fmaf(w2, c[3], a2)));
            a3 = fmaf(w0, c[2], fmaf(w1, c[3], fmaf(w2, pp,   a3)));
        }
        f32x4 r = {fmaxf(a0, 0.f), fmaxf(a1, 0.f), fmaxf(a2, 0.f), fmaxf(a3, 0.f)};
        *reinterpret_cast<f32x4*>(&tf[oo * 64 + t4 * 4]) = r;
        *reinterpret_cast<f32x4*>(&out[TF_OFF + (b * 32 + oo) * 64 + t4 * 4]) = r;
    }
    __syncthreads();

    if (tid < 32) {
        float s = 0.f;
#pragma unroll
        for (int t4 = 0; t4 < 16; ++t4) {
            f32x4 c = *reinterpret_cast<const f32x4*>(&tf[tid * 64 + t4 * 4]);
            s += c[0] + c[1] + c[2] + c[3];
        }
        pooled[tid] = s * (1.f / 64.f);
    }
    __syncthreads();

    if (tid < 64) {
        float a = fb1[tid];
#pragma unroll
        for (int i2 = 0; i2 < 32; ++i2) a += pooled[i2] * fw1[tid * 32 + i2];
        g1[tid] = fmaxf(a, 0.f);
    }
    __syncthreads();
    if (tid < 32) {
        float a = fb2[tid];
        for (int i2 = 0; i2 < 64; ++i2) a += g1[i2] * fw2[tid * 64 + i2];
        g2[tid] = fmaxf(a, 0.f);
    }
    __syncthreads();
    if (tid == 0) {
        float a = fb3[0];
        for (int i2 = 0; i2 < 32; ++i2) a += g2[i2] * fw3[i2];
        float flow = 1.f / (1.f + expf(-a));
        sca[0] = flow;
        out[b] = flow;
    }
    if (tid >= 4 && tid < 7) {
        int c = tid - 4;
        float mu = 0.f;
        for (int t = 0; t < 64; ++t) mu += cs_s[c * 64 + t];
        mu *= (1.f / 64.f);
        float v = 0.f;
        for (int t = 0; t < 64; ++t) { float d = cs_s[c * 64 + t] - mu; v += d * d; }
        sca[1 + c] = sqrtf(v / 63.f);
    }
    __syncthreads();
    if (tid == 0) {
        float s0 = sca[1], s1 = sca[2], s2 = sca[3];
        float mu = (s0 + s1 + s2) * (1.f / 3.f);
        float var = ((s0 - mu) * (s0 - mu) + (s1 - mu) * (s1 - mu) + (s2 - mu) * (s2 - mu)) * 0.5f;
        float sy = 1.f / (1.f + expf(var));     // sigmoid(-var)
        out[4 + b] = sy;
        out[NAT_OFF + b] = (sca[0] + sy) * 0.5f;
    }
}

extern "C" void kernel_launch(void* const* d_in, const int* in_sizes, int n_in,
                              void* d_out, int out_size, void* d_ws, size_t ws_size,
                              hipStream_t stream)
{
    float* wsf = (float*)d_ws;
    float* out = (float*)d_out;

    seg_kernel<<<dim3(4096), 256, 0, stream>>>((const float*)d_in[0],
        (const float*)d_in[1], (const float*)d_in[2],
        (const float*)d_in[3], (const float*)d_in[4],
        (const float*)d_in[5], (const float*)d_in[6],
        wsf, out);

    tail_kernel<<<dim3(4), 1024, 0, stream>>>(wsf,
        (const float*)d_in[7],  (const float*)d_in[8],
        (const float*)d_in[9],  (const float*)d_in[10],
        (const float*)d_in[11], (const float*)d_in[12],
        (const float*)d_in[13], (const float*)d_in[14],
        (const float*)d_in[15], (const float*)d_in[16],
        (const float*)d_in[17], (const float*)d_in[18],
        (const float*)d_in[19], (const float*)d_in[20],
        (const float*)d_in[21], (const float*)d_in[22],
        (const float*)d_in[23], (const float*)d_in[24],
        out);
}

// Round 18
// 176.110 us; speedup vs baseline: 2.6307x; 1.6735x over previous
//
#include <hip/hip_runtime.h>
#include <hip/hip_bf16.h>

// BloodFlowSkinAnalyzer — f32 in/out (verified r5). Out layout (floats):
//   flow[4]@0, sync[4]@4, color[4*64*3]@8, masks[4,64,1,128,128]@776,
//   naturalness[4]@4195080, temporal[4,32,64]@4195084
// ws: colsum[4096][4] floats @0.
// conv1 bf16 MFMA (HW-verified r7/r8); conv2 FP8 e4m3 MFMA (numerics
// verified r16/r17: absmax 0.0039). r18: NO min-waves launch bound — r16/r17
// proved any bound makes the allocator partition the unified VGPR/AGPR file
// and spill (FETCH 45->546/736MB). fp8's -18 VGPR should fund 6-7 waves/SIMD
// naturally (floor(512/~72)); LDS 15.4KB is not binding.

typedef __attribute__((ext_vector_type(8))) short bf16x8;
typedef __attribute__((ext_vector_type(4))) float f32x4;

#define NAT_OFF  4195080
#define TF_OFF   4195084

__device__ __forceinline__ unsigned short f2bf(float f) {   // RNE f32->bf16
    unsigned u = __float_as_uint(f);
    u += 0x7FFFu + ((u >> 16) & 1u);
    return (unsigned short)(u >> 16);
}
__device__ __forceinline__ float bf2f(unsigned short u) {
    return __uint_as_float((unsigned)u << 16);
}

// Fused seg: conv1(3->32,k3,p1) bf16 MFMA + conv2(32->16,k3,p1) fp8 MFMA +
// conv3(16->1,k1)+sigmoid + masked sums. Block = 4 of 64 16x16 tiles.
__global__ __launch_bounds__(256) void seg_kernel(
    const float* __restrict__ x,
    const float* __restrict__ w1f, const float* __restrict__ b1f,
    const float* __restrict__ w2f, const float* __restrict__ b2f,
    const float* __restrict__ w3f, const float* __restrict__ b3f,
    float* __restrict__ colsum, float* __restrict__ out)
{
    const int tid  = threadIdx.x;
    const int lane = tid & 63;
    const int wid  = tid >> 6;
    const int img  = blockIdx.x >> 4;        // b*64+t
    const int part = blockIdx.x & 15;        // 4 tiles per part

    __shared__ __align__(4)  unsigned short in_bs[2][1200]; // dbuf 3x20x20 bf16
    __shared__ __align__(16) unsigned char h1_s[10368];     // [(y*18+x)*32+oc] fp8
    __shared__ float red[4][4];

    const int ocl = lane & 15;   // free idx
    const int g   = lane >> 4;   // k-group (8 k's each)

    // ---- conv1 B-frags (k = ic*9+ky*3+kx, w1 native [oc][k]); k>=27 -> 0 ----
    bf16x8 c1b0, c1b1;
    int offB[8];                 // per-lane in_bs element offsets for A gather
#pragma unroll
    for (int e = 0; e < 8; ++e) {
        int k = g * 8 + e;
        if (k < 27) {
            int ic = k / 9, r2 = k - ic * 9, ky = r2 / 3, kx = r2 - ky * 3;
            offB[e] = ic * 400 + ky * 20 + kx;
            c1b0[e] = (short)f2bf(w1f[(2 * ocl)     * 27 + k]);
            c1b1[e] = (short)f2bf(w1f[(2 * ocl + 1) * 27 + k]);
        } else {
            offB[e] = 0;
            c1b0[e] = 0; c1b1[e] = 0;
        }
    }
    const float b1_e = b1f[2 * ocl], b1_o = b1f[2 * ocl + 1];

    // ---- conv2 W-frags as FP8 (MFMA A operand after swap): 9 x 8 fp8 ----
    long bfrag[9];
#pragma unroll
    for (int c = 0; c < 9; ++c) {
        float w[8];
#pragma unroll
        for (int e = 0; e < 8; ++e)
            w[e] = w2f[(ocl * 32 + g * 8 + e) * 9 + c];
        int lo = __builtin_amdgcn_cvt_pk_fp8_f32(w[0], w[1], 0, false);
        lo     = __builtin_amdgcn_cvt_pk_fp8_f32(w[2], w[3], lo, true);
        int hi = __builtin_amdgcn_cvt_pk_fp8_f32(w[4], w[5], 0, false);
        hi     = __builtin_amdgcn_cvt_pk_fp8_f32(w[6], w[7], hi, true);
        bfrag[c] = (long)(unsigned)lo | ((long)hi << 32);
    }
    // conv3 per-lane constants for oc = g*4+r (D rows after swap)
    float b2v[4], w3v[4];
#pragma unroll
    for (int r = 0; r < 4; ++r) { b2v[r] = b2f[g * 4 + r]; w3v[r] = w3f[g * 4 + r]; }
    const float b3v = b3f[0];

    const float* xin = x + (size_t)img * 3 * 16384;
    float s0 = 0.f, s1 = 0.f, s2 = 0.f, sm = 0.f;

    // ---- prologue: stage tile 0 into buffer 0 ----
    {
        const int tile0 = part * 4;
        const int r0 = (tile0 >> 3) * 16, c0 = (tile0 & 7) * 16;
        for (int idx = tid; idx < 1200; idx += 256) {
            int ic = idx / 400, rem = idx - ic * 400;
            int r = rem / 20, cc = rem - r * 20;
            int gr = r0 - 2 + r, gc = c0 - 2 + cc;
            float vv = 0.f;
            if ((unsigned)gr < 128u && (unsigned)gc < 128u)
                vv = xin[ic * 16384 + gr * 128 + gc];
            in_bs[0][idx] = f2bf(vv);
        }
    }
    __syncthreads();

    for (int tt = 0; tt < 4; ++tt) {
        const int cur = tt & 1;
        const unsigned short* inb = in_bs[cur];
        const int tile = part * 4 + tt;
        const int r0 = (tile >> 3) * 16, c0 = (tile & 7) * 16;
        const bool interior = (r0 >= 16 && r0 <= 96 && c0 >= 16 && c0 <= 96);

        // ---- issue next tile's loads NOW (latency hides under conv1+conv2).
        float nv[5];
        if (tt < 3) {
            const int tn = tile + 1;
            const int r0n = (tn >> 3) * 16, c0n = (tn & 7) * 16;
#pragma unroll
            for (int s = 0; s < 5; ++s) {
                int idx = tid + 256 * s;
                nv[s] = 0.f;
                if (idx < 1200) {
                    int ic = idx / 400, rem = idx - ic * 400;
                    int r = rem / 20, cc = rem - r * 20;
                    int gr = r0n - 2 + r, gc = c0n - 2 + cc;
                    if ((unsigned)gr < 128u && (unsigned)gc < 128u)
                        nv[s] = xin[ic * 16384 + gr * 128 + gc];
                }
            }
        }

        // ---- conv1 MFMA: 21 groups of 16 positions over 4 waves ----
        for (int grp = wid; grp < 21; grp += 4) {
            int pos = grp * 16 + ocl;                 // A row
            int hy = pos / 18, hx = pos - hy * 18;
            int base = hy * 20 + hx;
            base = base > 357 ? 357 : base;           // clamp tail-group lanes
            bf16x8 afrag;
#pragma unroll
            for (int e = 0; e < 8; ++e)
                afrag[e] = (short)inb[base + offB[e]];
            f32x4 d0 = {0.f, 0.f, 0.f, 0.f}, d1 = {0.f, 0.f, 0.f, 0.f};
            d0 = __builtin_amdgcn_mfma_f32_16x16x32_bf16(afrag, c1b0, d0, 0, 0, 0);
            d1 = __builtin_amdgcn_mfma_f32_16x16x32_bf16(afrag, c1b1, d1, 0, 0, 0);
            int p0 = grp * 16 + g * 4;
            if (interior) {
#pragma unroll
                for (int r = 0; r < 4; ++r) {
                    int p2 = p0 + r;
                    if (p2 < 324) {
                        int pk = __builtin_amdgcn_cvt_pk_fp8_f32(
                            fmaxf(d0[r] + b1_e, 0.f), fmaxf(d1[r] + b1_o, 0.f), 0, false);
                        *reinterpret_cast<unsigned short*>(&h1_s[p2 * 32 + 2 * ocl]) =
                            (unsigned short)pk;
                    }
                }
            } else {
                int hy2 = p0 / 18, hx2 = p0 - hy2 * 18;
#pragma unroll
                for (int r = 0; r < 4; ++r) {
                    int p2 = p0 + r;
                    if (p2 < 324) {
                        bool valid = ((unsigned)(r0 - 1 + hy2) < 128u) &&
                                     ((unsigned)(c0 - 1 + hx2) < 128u);
                        float he = valid ? fmaxf(d0[r] + b1_e, 0.f) : 0.f;
                        float ho = valid ? fmaxf(d1[r] + b1_o, 0.f) : 0.f;
                        int pk = __builtin_amdgcn_cvt_pk_fp8_f32(he, ho, 0, false);
                        *reinterpret_cast<unsigned short*>(&h1_s[p2 * 32 + 2 * ocl]) =
                            (unsigned short)pk;
                    }
                    ++hx2;
                    if (hx2 == 18) { hx2 = 0; ++hy2; }
                }
            }
        }
        __syncthreads();

        // ---- conv2 FP8 MFMA: swapped operands (A=w2 fp8, B=h1 fp8).
        //      Row-reuse: 18 ds_read_b64; per-q accumulation order fixed.
        const unsigned char* hb = &h1_s[((wid * 4) * 18 + ocl) * 32 + g * 8];
        f32x4 acc4[4];
#pragma unroll
        for (int q = 0; q < 4; ++q) acc4[q] = (f32x4){0.f, 0.f, 0.f, 0.f};
#pragma unroll
        for (int rp = 0; rp < 6; ++rp) {
            long fr0 = *reinterpret_cast<const long*>(hb + (rp * 18 + 0) * 32);
            long fr1 = *reinterpret_cast<const long*>(hb + (rp * 18 + 1) * 32);
            long fr2 = *reinterpret_cast<const long*>(hb + (rp * 18 + 2) * 32);
#pragma unroll
            for (int ky = 0; ky < 3; ++ky) {
                const int q = rp - ky;
                if (q >= 0 && q < 4) {
                    acc4[q] = __builtin_amdgcn_mfma_f32_16x16x32_fp8_fp8(
                        bfrag[ky * 3 + 0], fr0, acc4[q], 0, 0, 0);
                    acc4[q] = __builtin_amdgcn_mfma_f32_16x16x32_fp8_fp8(
                        bfrag[ky * 3 + 1], fr1, acc4[q], 0, 0, 0);
                    acc4[q] = __builtin_amdgcn_mfma_f32_16x16x32_fp8_fp8(
                        bfrag[ky * 3 + 2], fr2, acc4[q], 0, 0, 0);
                }
            }
        }
        // conv3: lane holds P[oc=g*4+r][x=ocl]; 4 in-lane FMA + 2 shfl
#pragma unroll
        for (int q = 0; q < 4; ++q) {
            const int s = wid * 4 + q;
            float part3 = 0.f;
#pragma unroll
            for (int r = 0; r < 4; ++r)
                part3 = fmaf(fmaxf(acc4[q][r] + b2v[r], 0.f), w3v[r], part3);
            part3 += __shfl_xor(part3, 16);
            part3 += __shfl_xor(part3, 32);
            if (lane < 16) {
                int xw = lane;
                float msk = 1.f / (1.f + __expf(-(part3 + b3v)));
                out[776 + (size_t)img * 16384 + (size_t)(r0 + s) * 128 + (c0 + xw)] = msk;
                float f0  = bf2f(inb[      (s + 2) * 20 + (xw + 2)]);
                float f1v = bf2f(inb[400 + (s + 2) * 20 + (xw + 2)]);
                float f2v = bf2f(inb[800 + (s + 2) * 20 + (xw + 2)]);
                s0 = fmaf(msk, f0, s0);
                s1 = fmaf(msk, f1v, s1);
                s2 = fmaf(msk, f2v, s2);
                sm += msk;
            }
        }

        // ---- write next tile's halo into the other buffer ----
        if (tt < 3) {
#pragma unroll
            for (int s = 0; s < 5; ++s) {
                int idx = tid + 256 * s;
                if (idx < 1200) in_bs[cur ^ 1][idx] = f2bf(nv[s]);
            }
        }
        __syncthreads();
    }

    // ---- block reduction of the 4 sums ----
#pragma unroll
    for (int off = 32; off > 0; off >>= 1) {
        s0 += __shfl_down(s0, off);
        s1 += __shfl_down(s1, off);
        s2 += __shfl_down(s2, off);
        sm += __shfl_down(sm, off);
    }
    if (lane == 0) { red[wid][0] = s0; red[wid][1] = s1; red[wid][2] = s2; red[wid][3] = sm; }
    __syncthreads();
    if (tid < 4) {
        float s = red[0][tid] + red[1][tid] + red[2][tid] + red[3][tid];
        colsum[(size_t)blockIdx.x * 4 + tid] = s;   // [img][part][4]
    }
}

// Tail: 1024 threads; ta2/ta3 vectorized (b128 + lane-shfl conv halo).
__global__ __launch_bounds__(1024) void tail_kernel(
    const float* __restrict__ colsum,
    const float* __restrict__ cw1, const float* __restrict__ cb1,
    const float* __restrict__ cw2, const float* __restrict__ cb2,
    const float* __restrict__ cw3, const float* __restrict__ cb3,
    const float* __restrict__ tw1, const float* __restrict__ tb1,
    const float* __restrict__ tw2, const float* __restrict__ tb2,
    const float* __restrict__ tw3, const float* __restrict__ tb3,
    const float* __restrict__ fw1, const float* __restrict__ fb1,
    const float* __restrict__ fw2, const float* __restrict__ fb2,
    const float* __restrict__ fw3, const float* __restrict__ fb3,
    float* __restrict__ out)
{
    const int b = blockIdx.x, tid = threadIdx.x;
    __shared__ float tmp[64][4];
    __shared__ float cs_s[3 * 64];
    __shared__ float e3s[3 * 64];
    __shared__ __align__(16) float f1[32 * 64];
    __shared__ __align__(16) float f2[64 * 64];
    __shared__ __align__(16) float tf[32 * 64];
    __shared__ float pooled[32], g1[64], g2[32], sca[8];

    if (tid < 256) {
        int t = tid >> 2, slot = tid & 3;
        const float* pp = colsum + (size_t)((b * 64 + t) * 16) * 4 + slot;
        float s = 0.f;
#pragma unroll
        for (int p = 0; p < 16; ++p) s += pp[p * 4];
        tmp[t][slot] = s;
    }
    __syncthreads();
    if (tid < 192) {
        int c = tid >> 6, t = tid & 63;
        float v = tmp[t][c] / (tmp[t][3] + 1e-8f);
        cs_s[tid] = v;
        out[8 + (b * 64 + t) * 3 + c] = v;
    }
    __syncthreads();

    if (tid < 64) {
        int t = tid;
        float c0v = cs_s[t], c1v = cs_s[64 + t], c2v = cs_s[128 + t];
        float e1[16];
#pragma unroll
        for (int o = 0; o < 16; ++o)
            e1[o] = fmaxf(cb1[o] + cw1[o * 3 + 0] * c0v + cw1[o * 3 + 1] * c1v
                                 + cw1[o * 3 + 2] * c2v, 0.f);
        float e2[8];
#pragma unroll
        for (int o = 0; o < 8; ++o) {
            float a = cb2[o];
#pragma unroll
            for (int i2 = 0; i2 < 16; ++i2) a += cw2[o * 16 + i2] * e1[i2];
            e2[o] = fmaxf(a, 0.f);
        }
#pragma unroll
        for (int o = 0; o < 3; ++o) {
            float a = cb3[o];
#pragma unroll
            for (int i2 = 0; i2 < 8; ++i2) a += cw3[o * 8 + i2] * e2[i2];
            e3s[o * 64 + t] = a;   // no relu on last ct conv
        }
    }
    __syncthreads();

    // ta1: 3->32 k3 p1
    {
        int o = tid >> 6, t = tid & 63;
#pragma unroll
        for (int h = 0; h < 2; ++h) {
            int oo = o + 16 * h;
            float a = tb1[oo];
#pragma unroll
            for (int ic = 0; ic < 3; ++ic)
#pragma unroll
                for (int k = 0; k < 3; ++k) {
                    int ttk = t + k - 1;
                    if ((unsigned)ttk < 64u)
                        a += e3s[ic * 64 + ttk] * tw1[(oo * 3 + ic) * 3 + k];
                }
            f1[oo * 64 + t] = fmaxf(a, 0.f);
        }
    }
    __syncthreads();

    // ta2: 32->64 k3 p1 — thread (oo=tid>>4, t4=tid&15) computes t=4t4..4t4+3
    {
        int oo = tid >> 4, t4 = tid & 15;
        float a0 = tb2[oo], a1 = a0, a2 = a0, a3 = a0;
        for (int ic = 0; ic < 32; ++ic) {
            f32x4 c = *reinterpret_cast<const f32x4*>(&f1[ic * 64 + t4 * 4]);
            float pm = __shfl_up(c[3], 1);
            float pp = __shfl_down(c[0], 1);
            if (t4 == 0)  pm = 0.f;          // t-1 < 0 pad
            if (t4 == 15) pp = 0.f;          // t+1 > 63 pad
            const float* wp = tw2 + (oo * 32 + ic) * 3;
            float w0 = wp[0], w1 = wp[1], w2 = wp[2];
            a0 = fmaf(w0, pm,   fmaf(w1, c[0], fmaf(w2, c[1], a0)));
            a1 = fmaf(w0, c[0], fmaf(w1, c[1], fmaf(w2, c[2], a1)));
            a2 = fmaf(w0, c[1], fmaf(w1, c[2], fmaf(w2, c[3], a2)));
            a3 = fmaf(w0, c[2], fmaf(w1, c[3], fmaf(w2, pp,   a3)));
        }
        f32x4 r = {fmaxf(a0, 0.f), fmaxf(a1, 0.f), fmaxf(a2, 0.f), fmaxf(a3, 0.f)};
        *reinterpret_cast<f32x4*>(&f2[oo * 64 + t4 * 4]) = r;
    }
    __syncthreads();

    // ta3: 64->32 k3 p1 (+ temporal_features out), threads 0..511
    if (tid < 512) {
        int oo = tid >> 4, t4 = tid & 15;
        float a0 = tb3[oo], a1 = a0, a2 = a0, a3 = a0;
        for (int ic = 0; ic < 64; ++ic) {
            f32x4 c = *reinterpret_cast<const f32x4*>(&f2[ic * 64 + t4 * 4]);
            float pm = __shfl_up(c[3], 1);
            float pp = __shfl_down(c[0], 1);
            if (t4 == 0)  pm = 0.f;
            if (t4 == 15) pp = 0.f;
            const float* wp = tw3 + (oo * 64 + ic) * 3;
            float w0 = wp[0], w1 = wp[1], w2 = wp[2];
            a0 = fmaf(w0, pm,   fmaf(w1, c[0], fmaf(w2, c[1], a0)));
            a1 = fmaf(w0, c[0], fmaf(w1, c[1], fmaf(w2, c[2], a1)));
            a2 = fmaf(w0, c[1], fmaf(w1, c[2], fmaf(w2, c[3], a2)));
            a3 = fmaf(w0, c[2], fmaf(w1, c[3], fmaf(w2, pp,   a3)));
        }
        f32x4 r = {fmaxf(a0, 0.f), fmaxf(a1, 0.f), fmaxf(a2, 0.f), fmaxf(a3, 0.f)};
        *reinterpret_cast<f32x4*>(&tf[oo * 64 + t4 * 4]) = r;
        *reinterpret_cast<f32x4*>(&out[TF_OFF + (b * 32 + oo) * 64 + t4 * 4]) = r;
    }
    __syncthreads();

    if (tid < 32) {
        float s = 0.f;
#pragma unroll
        for (int t4 = 0; t4 < 16; ++t4) {
            f32x4 c = *reinterpret_cast<const f32x4*>(&tf[tid * 64 + t4 * 4]);
            s += c[0] + c[1] + c[2] + c[3];
        }
        pooled[tid] = s * (1.f / 64.f);
    }
    __syncthreads();

    if (tid < 64) {
        float a = fb1[tid];
#pragma unroll
        for (int i2 = 0; i2 < 32; ++i2) a += pooled[i2] * fw1[tid * 32 + i2];
        g1[tid] = fmaxf(a, 0.f);
    }
    __syncthreads();
    if (tid < 32) {
        float a = fb2[tid];
        for (int i2 = 0; i2 < 64; ++i2) a += g1[i2] * fw2[tid * 64 + i2];
        g2[tid] = fmaxf(a, 0.f);
    }
    __syncthreads();
    if (tid == 0) {
        float a = fb3[0];
        for (int i2 = 0; i2 < 32; ++i2) a += g2[i2] * fw3[i2];
        float flow = 1.f / (1.f + expf(-a));
        sca[0] = flow;
        out[b] = flow;
    }
    if (tid >= 4 && tid < 7) {
        int c = tid - 4;
        float mu = 0.f;
        for (int t = 0; t < 64; ++t) mu += cs_s[c * 64 + t];
        mu *= (1.f / 64.f);
        float v = 0.f;
        for (int t = 0; t < 64; ++t) { float d = cs_s[c * 64 + t] - mu; v += d * d; }
        sca[1 + c] = sqrtf(v / 63.f);
    }
    __syncthreads();
    if (tid == 0) {
        float s0 = sca[1], s1 = sca[2], s2 = sca[3];
        float mu = (s0 + s1 + s2) * (1.f / 3.f);
        float var = ((s0 - mu) * (s0 - mu) + (s1 - mu) * (s1 - mu) + (s2 - mu) * (s2 - mu)) * 0.5f;
        float sy = 1.f / (1.f + expf(var));     // sigmoid(-var)
        out[4 + b] = sy;
        out[NAT_OFF + b] = (sca[0] + sy) * 0.5f;
    }
}

extern "C" void kernel_launch(void* const* d_in, const int* in_sizes, int n_in,
                              void* d_out, int out_size, void* d_ws, size_t ws_size,
                              hipStream_t stream)
{
    float* wsf = (float*)d_ws;
    float* out = (float*)d_out;

    seg_kernel<<<dim3(4096), 256, 0, stream>>>((const float*)d_in[0],
        (const float*)d_in[1], (const float*)d_in[2],
        (const float*)d_in[3], (const float*)d_in[4],
        (const float*)d_in[5], (const float*)d_in[6],
        wsf, out);

    tail_kernel<<<dim3(4), 1024, 0, stream>>>(wsf,
        (const float*)d_in[7],  (const float*)d_in[8],
        (const float*)d_in[9],  (const float*)d_in[10],
        (const float*)d_in[11], (const float*)d_in[12],
        (const float*)d_in[13], (const float*)d_in[14],
        (const float*)d_in[15], (const float*)d_in[16],
        (const float*)d_in[17], (const float*)d_in[18],
        (const float*)d_in[19], (const float*)d_in[20],
        (const float*)d_in[21], (const float*)d_in[22],
        (const float*)d_in[23], (const float*)d_in[24],
        out);
}

// Round 19
// 160.471 us; speedup vs baseline: 2.8871x; 1.0975x over previous
//
#include <hip/hip_runtime.h>
#include <hip/hip_bf16.h>

// BloodFlowSkinAnalyzer — f32 in/out (verified r5). Out layout (floats):
//   flow[4]@0, sync[4]@4, color[4*64*3]@8, masks[4,64,1,128,128]@776,
//   naturalness[4]@4195080, temporal[4,32,64]@4195084
// conv1 bf16 MFMA + conv2 FP8 e4m3 MFMA (layouts/numerics HW-verified r7-r18).
// r19: 1 tile/block (grid 16384) — swap intra-block pipelining for inter-block
//      TLP. Occupancy was pinned at 30% across 4 resource footprints (r14-r18)
//      => big-block dispatch dynamics were the cap. Per-block weight-frag setup
//      amortized via prep kernel writing lane-class fragments to ws.
// ws (floats): colsum[16384][4] @0 | w1frag(u16 64x16) @65536 | w2frag(fp8
//      64x72B) @66560.

typedef __attribute__((ext_vector_type(8))) short bf16x8;
typedef __attribute__((ext_vector_type(4))) float f32x4;

#define NAT_OFF  4195080
#define TF_OFF   4195084
#define W1F_OFF  65536
#define W2F_OFF  66560

__device__ __forceinline__ unsigned short f2bf(float f) {   // RNE f32->bf16
    unsigned u = __float_as_uint(f);
    u += 0x7FFFu + ((u >> 16) & 1u);
    return (unsigned short)(u >> 16);
}
__device__ __forceinline__ float bf2f(unsigned short u) {
    return __uint_as_float((unsigned)u << 16);
}

// Pre-bake per-lane-class (class = lane = g*16+ocl) MFMA fragments into ws.
__global__ __launch_bounds__(64) void prep_kernel(
    const float* __restrict__ w1f, const float* __restrict__ w2f,
    float* __restrict__ wsf)
{
    const int L = threadIdx.x;           // lane class 0..63
    const int ocl = L & 15, g = L >> 4;
    unsigned short* w1fr = (unsigned short*)(wsf + W1F_OFF);
#pragma unroll
    for (int e = 0; e < 8; ++e) {
        int k = g * 8 + e;
        unsigned short v0 = 0, v1 = 0;
        if (k < 27) {
            v0 = f2bf(w1f[(2 * ocl)     * 27 + k]);
            v1 = f2bf(w1f[(2 * ocl + 1) * 27 + k]);
        }
        w1fr[L * 16 + e]     = v0;
        w1fr[L * 16 + 8 + e] = v1;
    }
    char* w2fr = (char*)(wsf + W2F_OFF);
#pragma unroll
    for (int c = 0; c < 9; ++c) {
        float w[8];
#pragma unroll
        for (int e = 0; e < 8; ++e)
            w[e] = w2f[(ocl * 32 + g * 8 + e) * 9 + c];
        int lo = __builtin_amdgcn_cvt_pk_fp8_f32(w[0], w[1], 0, false);
        lo     = __builtin_amdgcn_cvt_pk_fp8_f32(w[2], w[3], lo, true);
        int hi = __builtin_amdgcn_cvt_pk_fp8_f32(w[4], w[5], 0, false);
        hi     = __builtin_amdgcn_cvt_pk_fp8_f32(w[6], w[7], hi, true);
        long v = (long)(unsigned)lo | ((long)hi << 32);
        *reinterpret_cast<long*>(w2fr + L * 72 + c * 8) = v;
    }
}

// Fused seg: one 16x16 tile per block. stage -> conv1 bf16 MFMA -> conv2 fp8
// MFMA -> conv3 epilogue + masked sums. 2 barriers per block.
__global__ __launch_bounds__(256) void seg_kernel(
    const float* __restrict__ x,
    const float* __restrict__ b1f, const float* __restrict__ b2f,
    const float* __restrict__ w3f, const float* __restrict__ b3f,
    const float* __restrict__ wsf,
    float* __restrict__ colsum, float* __restrict__ out)
{
    const int tid  = threadIdx.x;
    const int lane = tid & 63;
    const int wid  = tid >> 6;
    const int img  = blockIdx.x >> 6;        // b*64+t
    const int tile = blockIdx.x & 63;
    const int r0 = (tile >> 3) * 16, c0 = (tile & 7) * 16;
    const bool interior = (r0 >= 16 && r0 <= 96 && c0 >= 16 && c0 <= 96);

    __shared__ __align__(4)  unsigned short in_bs[1200];  // 3x20x20 bf16 halo
    __shared__ __align__(16) unsigned char h1_s[10368];   // [(y*18+x)*32+oc] fp8
    __shared__ float red[4][4];

    const int ocl = lane & 15;   // free idx
    const int g   = lane >> 4;   // k-group (8 k's each)

    // ---- fragments from ws (prep-baked; lane == class) ----
    const unsigned short* w1fr = (const unsigned short*)(wsf + W1F_OFF);
    bf16x8 c1b0 = *reinterpret_cast<const bf16x8*>(&w1fr[lane * 16]);
    bf16x8 c1b1 = *reinterpret_cast<const bf16x8*>(&w1fr[lane * 16 + 8]);
    const char* w2fr = (const char*)(wsf + W2F_OFF);
    long bfrag[9];
#pragma unroll
    for (int c = 0; c < 9; ++c)
        bfrag[c] = *reinterpret_cast<const long*>(w2fr + lane * 72 + c * 8);

    int offB[8];                 // per-lane in_bs element offsets for A gather
#pragma unroll
    for (int e = 0; e < 8; ++e) {
        int k = g * 8 + e;
        if (k < 27) {
            int ic = k / 9, r2 = k - ic * 9, ky = r2 / 3, kx = r2 - ky * 3;
            offB[e] = ic * 400 + ky * 20 + kx;
        } else offB[e] = 0;
    }
    const float b1_e = b1f[2 * ocl], b1_o = b1f[2 * ocl + 1];
    float b2v[4], w3v[4];
#pragma unroll
    for (int r = 0; r < 4; ++r) { b2v[r] = b2f[g * 4 + r]; w3v[r] = w3f[g * 4 + r]; }
    const float b3v = b3f[0];

    const float* xin = x + (size_t)img * 3 * 16384;

    // ---- stage 20x20x3 halo as bf16 ----
    for (int idx = tid; idx < 1200; idx += 256) {
        int ic = idx / 400, rem = idx - ic * 400;
        int r = rem / 20, cc = rem - r * 20;
        int gr = r0 - 2 + r, gc = c0 - 2 + cc;
        float vv = 0.f;
        if ((unsigned)gr < 128u && (unsigned)gc < 128u)
            vv = xin[ic * 16384 + gr * 128 + gc];
        in_bs[idx] = f2bf(vv);
    }
    __syncthreads();

    // ---- conv1 MFMA: 21 groups of 16 positions over 4 waves ----
    for (int grp = wid; grp < 21; grp += 4) {
        int pos = grp * 16 + ocl;                 // A row
        int hy = pos / 18, hx = pos - hy * 18;
        int base = hy * 20 + hx;
        base = base > 357 ? 357 : base;           // clamp tail-group lanes
        bf16x8 afrag;
#pragma unroll
        for (int e = 0; e < 8; ++e)
            afrag[e] = (short)in_bs[base + offB[e]];
        f32x4 d0 = {0.f, 0.f, 0.f, 0.f}, d1 = {0.f, 0.f, 0.f, 0.f};
        d0 = __builtin_amdgcn_mfma_f32_16x16x32_bf16(afrag, c1b0, d0, 0, 0, 0);
        d1 = __builtin_amdgcn_mfma_f32_16x16x32_bf16(afrag, c1b1, d1, 0, 0, 0);
        int p0 = grp * 16 + g * 4;
        if (interior) {
#pragma unroll
            for (int r = 0; r < 4; ++r) {
                int p2 = p0 + r;
                if (p2 < 324) {
                    int pk = __builtin_amdgcn_cvt_pk_fp8_f32(
                        fmaxf(d0[r] + b1_e, 0.f), fmaxf(d1[r] + b1_o, 0.f), 0, false);
                    *reinterpret_cast<unsigned short*>(&h1_s[p2 * 32 + 2 * ocl]) =
                        (unsigned short)pk;
                }
            }
        } else {
            int hy2 = p0 / 18, hx2 = p0 - hy2 * 18;
#pragma unroll
            for (int r = 0; r < 4; ++r) {
                int p2 = p0 + r;
                if (p2 < 324) {
                    bool valid = ((unsigned)(r0 - 1 + hy2) < 128u) &&
                                 ((unsigned)(c0 - 1 + hx2) < 128u);
                    float he = valid ? fmaxf(d0[r] + b1_e, 0.f) : 0.f;
                    float ho = valid ? fmaxf(d1[r] + b1_o, 0.f) : 0.f;
                    int pk = __builtin_amdgcn_cvt_pk_fp8_f32(he, ho, 0, false);
                    *reinterpret_cast<unsigned short*>(&h1_s[p2 * 32 + 2 * ocl]) =
                        (unsigned short)pk;
                }
                ++hx2;
                if (hx2 == 18) { hx2 = 0; ++hy2; }
            }
        }
    }
    __syncthreads();

    // ---- conv2 FP8 MFMA (A=w2, B=h1; row-reuse, per-q order fixed) ----
    const unsigned char* hb = &h1_s[((wid * 4) * 18 + ocl) * 32 + g * 8];
    f32x4 acc4[4];
#pragma unroll
    for (int q = 0; q < 4; ++q) acc4[q] = (f32x4){0.f, 0.f, 0.f, 0.f};
#pragma unroll
    for (int rp = 0; rp < 6; ++rp) {
        long fr0 = *reinterpret_cast<const long*>(hb + (rp * 18 + 0) * 32);
        long fr1 = *reinterpret_cast<const long*>(hb + (rp * 18 + 1) * 32);
        long fr2 = *reinterpret_cast<const long*>(hb + (rp * 18 + 2) * 32);
#pragma unroll
        for (int ky = 0; ky < 3; ++ky) {
            const int q = rp - ky;
            if (q >= 0 && q < 4) {
                acc4[q] = __builtin_amdgcn_mfma_f32_16x16x32_fp8_fp8(
                    bfrag[ky * 3 + 0], fr0, acc4[q], 0, 0, 0);
                acc4[q] = __builtin_amdgcn_mfma_f32_16x16x32_fp8_fp8(
                    bfrag[ky * 3 + 1], fr1, acc4[q], 0, 0, 0);
                acc4[q] = __builtin_amdgcn_mfma_f32_16x16x32_fp8_fp8(
                    bfrag[ky * 3 + 2], fr2, acc4[q], 0, 0, 0);
            }
        }
    }
    // conv3: lane holds P[oc=g*4+r][x=ocl]; 4 in-lane FMA + 2 shfl
    float s0 = 0.f, s1 = 0.f, s2 = 0.f, sm = 0.f;
#pragma unroll
    for (int q = 0; q < 4; ++q) {
        const int s = wid * 4 + q;
        float part3 = 0.f;
#pragma unroll
        for (int r = 0; r < 4; ++r)
            part3 = fmaf(fmaxf(acc4[q][r] + b2v[r], 0.f), w3v[r], part3);
        part3 += __shfl_xor(part3, 16);
        part3 += __shfl_xor(part3, 32);
        if (lane < 16) {
            int xw = lane;
            float msk = 1.f / (1.f + __expf(-(part3 + b3v)));
            out[776 + (size_t)img * 16384 + (size_t)(r0 + s) * 128 + (c0 + xw)] = msk;
            float f0  = bf2f(in_bs[      (s + 2) * 20 + (xw + 2)]);
            float f1v = bf2f(in_bs[400 + (s + 2) * 20 + (xw + 2)]);
            float f2v = bf2f(in_bs[800 + (s + 2) * 20 + (xw + 2)]);
            s0 = fmaf(msk, f0, s0);
            s1 = fmaf(msk, f1v, s1);
            s2 = fmaf(msk, f2v, s2);
            sm += msk;
        }
    }

    // ---- block reduction of the 4 sums ----
#pragma unroll
    for (int off = 32; off > 0; off >>= 1) {
        s0 += __shfl_down(s0, off);
        s1 += __shfl_down(s1, off);
        s2 += __shfl_down(s2, off);
        sm += __shfl_down(sm, off);
    }
    if (lane == 0) { red[wid][0] = s0; red[wid][1] = s1; red[wid][2] = s2; red[wid][3] = sm; }
    __syncthreads();
    if (tid < 4) {
        float s = red[0][tid] + red[1][tid] + red[2][tid] + red[3][tid];
        colsum[(size_t)blockIdx.x * 4 + tid] = s;   // [img*64+tile][4]
    }
}

// Tail: 1024 threads; ta2/ta3 vectorized (b128 + lane-shfl conv halo).
__global__ __launch_bounds__(1024) void tail_kernel(
    const float* __restrict__ colsum,
    const float* __restrict__ cw1, const float* __restrict__ cb1,
    const float* __restrict__ cw2, const float* __restrict__ cb2,
    const float* __restrict__ cw3, const float* __restrict__ cb3,
    const float* __restrict__ tw1, const float* __restrict__ tb1,
    const float* __restrict__ tw2, const float* __restrict__ tb2,
    const float* __restrict__ tw3, const float* __restrict__ tb3,
    const float* __restrict__ fw1, const float* __restrict__ fb1,
    const float* __restrict__ fw2, const float* __restrict__ fb2,
    const float* __restrict__ fw3, const float* __restrict__ fb3,
    float* __restrict__ out)
{
    const int b = blockIdx.x, tid = threadIdx.x;
    __shared__ float tmp[64][4];
    __shared__ float cs_s[3 * 64];
    __shared__ float e3s[3 * 64];
    __shared__ __align__(16) float f1[32 * 64];
    __shared__ __align__(16) float f2[64 * 64];
    __shared__ __align__(16) float tf[32 * 64];
    __shared__ float pooled[32], g1[64], g2[32], sca[8];

    if (tid < 256) {
        int t = tid >> 2, slot = tid & 3;
        const float* pp = colsum + (size_t)((b * 64 + t) * 64) * 4 + slot;
        float s = 0.f;
#pragma unroll
        for (int tl = 0; tl < 64; ++tl) s += pp[tl * 4];
        tmp[t][slot] = s;
    }
    __syncthreads();
    if (tid < 192) {
        int c = tid >> 6, t = tid & 63;
        float v = tmp[t][c] / (tmp[t][3] + 1e-8f);
        cs_s[tid] = v;
        out[8 + (b * 64 + t) * 3 + c] = v;
    }
    __syncthreads();

    if (tid < 64) {
        int t = tid;
        float c0v = cs_s[t], c1v = cs_s[64 + t], c2v = cs_s[128 + t];
        float e1[16];
#pragma unroll
        for (int o = 0; o < 16; ++o)
            e1[o] = fmaxf(cb1[o] + cw1[o * 3 + 0] * c0v + cw1[o * 3 + 1] * c1v
                                 + cw1[o * 3 + 2] * c2v, 0.f);
        float e2[8];
#pragma unroll
        for (int o = 0; o < 8; ++o) {
            float a = cb2[o];
#pragma unroll
            for (int i2 = 0; i2 < 16; ++i2) a += cw2[o * 16 + i2] * e1[i2];
            e2[o] = fmaxf(a, 0.f);
        }
#pragma unroll
        for (int o = 0; o < 3; ++o) {
            float a = cb3[o];
#pragma unroll
            for (int i2 = 0; i2 < 8; ++i2) a += cw3[o * 8 + i2] * e2[i2];
            e3s[o * 64 + t] = a;   // no relu on last ct conv
        }
    }
    __syncthreads();

    // ta1: 3->32 k3 p1
    {
        int o = tid >> 6, t = tid & 63;
#pragma unroll
        for (int h = 0; h < 2; ++h) {
            int oo = o + 16 * h;
            float a = tb1[oo];
#pragma unroll
            for (int ic = 0; ic < 3; ++ic)
#pragma unroll
                for (int k = 0; k < 3; ++k) {
                    int ttk = t + k - 1;
                    if ((unsigned)ttk < 64u)
                        a += e3s[ic * 64 + ttk] * tw1[(oo * 3 + ic) * 3 + k];
                }
            f1[oo * 64 + t] = fmaxf(a, 0.f);
        }
    }
    __syncthreads();

    // ta2: 32->64 k3 p1 — thread (oo=tid>>4, t4=tid&15) computes t=4t4..4t4+3
    {
        int oo = tid >> 4, t4 = tid & 15;
        float a0 = tb2[oo], a1 = a0, a2 = a0, a3 = a0;
        for (int ic = 0; ic < 32; ++ic) {
            f32x4 c = *reinterpret_cast<const f32x4*>(&f1[ic * 64 + t4 * 4]);
            float pm = __shfl_up(c[3], 1);
            float pp = __shfl_down(c[0], 1);
            if (t4 == 0)  pm = 0.f;          // t-1 < 0 pad
            if (t4 == 15) pp = 0.f;          // t+1 > 63 pad
            const float* wp = tw2 + (oo * 32 + ic) * 3;
            float w0 = wp[0], w1 = wp[1], w2 = wp[2];
            a0 = fmaf(w0, pm,   fmaf(w1, c[0], fmaf(w2, c[1], a0)));
            a1 = fmaf(w0, c[0], fmaf(w1, c[1], fmaf(w2, c[2], a1)));
            a2 = fmaf(w0, c[1], fmaf(w1, c[2], fmaf(w2, c[3], a2)));
            a3 = fmaf(w0, c[2], fmaf(w1, c[3], fmaf(w2, pp,   a3)));
        }
        f32x4 r = {fmaxf(a0, 0.f), fmaxf(a1, 0.f), fmaxf(a2, 0.f), fmaxf(a3, 0.f)};
        *reinterpret_cast<f32x4*>(&f2[oo * 64 + t4 * 4]) = r;
    }
    __syncthreads();

    // ta3: 64->32 k3 p1 (+ temporal_features out), threads 0..511
    if (tid < 512) {
        int oo = tid >> 4, t4 = tid & 15;
        float a0 = tb3[oo], a1 = a0, a2 = a0, a3 = a0;
        for (int ic = 0; ic < 64; ++ic) {
            f32x4 c = *reinterpret_cast<const f32x4*>(&f2[ic * 64 + t4 * 4]);
            float pm = __shfl_up(c[3], 1);
            float pp = __shfl_down(c[0], 1);
            if (t4 == 0)  pm = 0.f;
            if (t4 == 15) pp = 0.f;
            const float* wp = tw3 + (oo * 64 + ic) * 3;
            float w0 = wp[0], w1 = wp[1], w2 = wp[2];
            a0 = fmaf(w0, pm,   fmaf(w1, c[0], fmaf(w2, c[1], a0)));
            a1 = fmaf(w0, c[0], fmaf(w1, c[1], fmaf(w2, c[2], a1)));
            a2 = fmaf(w0, c[1], fmaf(w1, c[2], fmaf(w2, c[3], a2)));
            a3 = fmaf(w0, c[2], fmaf(w1, c[3], fmaf(w2, pp,   a3)));
        }
        f32x4 r = {fmaxf(a0, 0.f), fmaxf(a1, 0.f), fmaxf(a2, 0.f), fmaxf(a3, 0.f)};
        *reinterpret_cast<f32x4*>(&tf[oo * 64 + t4 * 4]) = r;
        *reinterpret_cast<f32x4*>(&out[TF_OFF + (b * 32 + oo) * 64 + t4 * 4]) = r;
    }
    __syncthreads();

    if (tid < 32) {
        float s = 0.f;
#pragma unroll
        for (int t4 = 0; t4 < 16; ++t4) {
            f32x4 c = *reinterpret_cast<const f32x4*>(&tf[tid * 64 + t4 * 4]);
            s += c[0] + c[1] + c[2] + c[3];
        }
        pooled[tid] = s * (1.f / 64.f);
    }
    __syncthreads();

    if (tid < 64) {
        float a = fb1[tid];
#pragma unroll
        for (int i2 = 0; i2 < 32; ++i2) a += pooled[i2] * fw1[tid * 32 + i2];
        g1[tid] = fmaxf(a, 0.f);
    }
    __syncthreads();
    if (tid < 32) {
        float a = fb2[tid];
        for (int i2 = 0; i2 < 64; ++i2) a += g1[i2] * fw2[tid * 64 + i2];
        g2[tid] = fmaxf(a, 0.f);
    }
    __syncthreads();
    if (tid == 0) {
        float a = fb3[0];
        for (int i2 = 0; i2 < 32; ++i2) a += g2[i2] * fw3[i2];
        float flow = 1.f / (1.f + expf(-a));
        sca[0] = flow;
        out[b] = flow;
    }
    if (tid >= 4 && tid < 7) {
        int c = tid - 4;
        float mu = 0.f;
        for (int t = 0; t < 64; ++t) mu += cs_s[c * 64 + t];
        mu *= (1.f / 64.f);
        float v = 0.f;
        for (int t = 0; t < 64; ++t) { float d = cs_s[c * 64 + t] - mu; v += d * d; }
        sca[1 + c] = sqrtf(v / 63.f);
    }
    __syncthreads();
    if (tid == 0) {
        float s0 = sca[1], s1 = sca[2], s2 = sca[3];
        float mu = (s0 + s1 + s2) * (1.f / 3.f);
        float var = ((s0 - mu) * (s0 - mu) + (s1 - mu) * (s1 - mu) + (s2 - mu) * (s2 - mu)) * 0.5f;
        float sy = 1.f / (1.f + expf(var));     // sigmoid(-var)
        out[4 + b] = sy;
        out[NAT_OFF + b] = (sca[0] + sy) * 0.5f;
    }
}

extern "C" void kernel_launch(void* const* d_in, const int* in_sizes, int n_in,
                              void* d_out, int out_size, void* d_ws, size_t ws_size,
                              hipStream_t stream)
{
    float* wsf = (float*)d_ws;
    float* out = (float*)d_out;

    prep_kernel<<<1, 64, 0, stream>>>(
        (const float*)d_in[1], (const float*)d_in[3], wsf);

    seg_kernel<<<dim3(16384), 256, 0, stream>>>((const float*)d_in[0],
        (const float*)d_in[2], (const float*)d_in[4],
        (const float*)d_in[5], (const float*)d_in[6],
        wsf, wsf, out);

    tail_kernel<<<dim3(4), 1024, 0, stream>>>(wsf,
        (const float*)d_in[7],  (const float*)d_in[8],
        (const float*)d_in[9],  (const float*)d_in[10],
        (const float*)d_in[11], (const float*)d_in[12],
        (const float*)d_in[13], (const float*)d_in[14],
        (const float*)d_in[15], (const float*)d_in[16],
        (const float*)d_in[17], (const float*)d_in[18],
        (const float*)d_in[19], (const float*)d_in[20],
        (const float*)d_in[21], (const float*)d_in[22],
        (const float*)d_in[23], (const float*)d_in[24],
        out);
}

// Round 20
// 146.365 us; speedup vs baseline: 3.1653x; 1.0964x over previous
//
#include <hip/hip_runtime.h>
#include <hip/hip_bf16.h>

// BloodFlowSkinAnalyzer — f32 in/out (verified r5). Out layout (floats):
//   flow[4]@0, sync[4]@4, color[4*64*3]@8, masks[4,64,1,128,128]@776,
//   naturalness[4]@4195080, temporal[4,32,64]@4195084
// conv1 bf16 MFMA + conv2 FP8 e4m3 MFMA (layouts/numerics HW-verified r7-r19).
// r20: r19 (1 tile/block, grid 16384, occupancy 50%, VALUBusy 78%) + staging
//      VALU cut: thread t<240 owns 5 consecutive elems of one LDS row -> one
//      div + row-level bounds + float4 load + packed bf16 writes (was 5x
//      div/mod/bounds/f2bf). conv1 tail checks hoisted to grp==20 only.
// ws (floats): colsum[16384][4] @0 | w1frag @65536 | w2frag @66560.

typedef __attribute__((ext_vector_type(8))) short bf16x8;
typedef __attribute__((ext_vector_type(4))) float f32x4;

#define NAT_OFF  4195080
#define TF_OFF   4195084
#define W1F_OFF  65536
#define W2F_OFF  66560

__device__ __forceinline__ unsigned short f2bf(float f) {   // RNE f32->bf16
    unsigned u = __float_as_uint(f);
    u += 0x7FFFu + ((u >> 16) & 1u);
    return (unsigned short)(u >> 16);
}
__device__ __forceinline__ float bf2f(unsigned short u) {
    return __uint_as_float((unsigned)u << 16);
}
__device__ __forceinline__ unsigned pack_bf2(float lo, float hi) {
    __hip_bfloat162 h2 = __float22bfloat162_rn(make_float2(lo, hi));
    return *reinterpret_cast<unsigned*>(&h2);   // .x low 16 bits (RNE = f2bf)
}

// Pre-bake per-lane-class (class = lane = g*16+ocl) MFMA fragments into ws.
__global__ __launch_bounds__(64) void prep_kernel(
    const float* __restrict__ w1f, const float* __restrict__ w2f,
    float* __restrict__ wsf)
{
    const int L = threadIdx.x;           // lane class 0..63
    const int ocl = L & 15, g = L >> 4;
    unsigned short* w1fr = (unsigned short*)(wsf + W1F_OFF);
#pragma unroll
    for (int e = 0; e < 8; ++e) {
        int k = g * 8 + e;
        unsigned short v0 = 0, v1 = 0;
        if (k < 27) {
            v0 = f2bf(w1f[(2 * ocl)     * 27 + k]);
            v1 = f2bf(w1f[(2 * ocl + 1) * 27 + k]);
        }
        w1fr[L * 16 + e]     = v0;
        w1fr[L * 16 + 8 + e] = v1;
    }
    char* w2fr = (char*)(wsf + W2F_OFF);
#pragma unroll
    for (int c = 0; c < 9; ++c) {
        float w[8];
#pragma unroll
        for (int e = 0; e < 8; ++e)
            w[e] = w2f[(ocl * 32 + g * 8 + e) * 9 + c];
        int lo = __builtin_amdgcn_cvt_pk_fp8_f32(w[0], w[1], 0, false);
        lo     = __builtin_amdgcn_cvt_pk_fp8_f32(w[2], w[3], lo, true);
        int hi = __builtin_amdgcn_cvt_pk_fp8_f32(w[4], w[5], 0, false);
        hi     = __builtin_amdgcn_cvt_pk_fp8_f32(w[6], w[7], hi, true);
        long v = (long)(unsigned)lo | ((long)hi << 32);
        *reinterpret_cast<long*>(w2fr + L * 72 + c * 8) = v;
    }
}

// Fused seg: one 16x16 tile per block. stage -> conv1 bf16 MFMA -> conv2 fp8
// MFMA -> conv3 epilogue + masked sums. 2 barriers per block.
__global__ __launch_bounds__(256) void seg_kernel(
    const float* __restrict__ x,
    const float* __restrict__ b1f, const float* __restrict__ b2f,
    const float* __restrict__ w3f, const float* __restrict__ b3f,
    const float* __restrict__ wsf,
    float* __restrict__ colsum, float* __restrict__ out)
{
    const int tid  = threadIdx.x;
    const int lane = tid & 63;
    const int wid  = tid >> 6;
    const int img  = blockIdx.x >> 6;        // b*64+t
    const int tile = blockIdx.x & 63;
    const int r0 = (tile >> 3) * 16, c0 = (tile & 7) * 16;
    const bool interior = (r0 >= 16 && r0 <= 96 && c0 >= 16 && c0 <= 96);

    __shared__ __align__(4)  unsigned short in_bs[1200];  // 3x20x20 bf16 halo
    __shared__ __align__(16) unsigned char h1_s[10368];   // [(y*18+x)*32+oc] fp8
    __shared__ float red[4][4];

    const int ocl = lane & 15;   // free idx
    const int g   = lane >> 4;   // k-group (8 k's each)

    // ---- fragments from ws (prep-baked; lane == class) ----
    const unsigned short* w1fr = (const unsigned short*)(wsf + W1F_OFF);
    bf16x8 c1b0 = *reinterpret_cast<const bf16x8*>(&w1fr[lane * 16]);
    bf16x8 c1b1 = *reinterpret_cast<const bf16x8*>(&w1fr[lane * 16 + 8]);
    const char* w2fr = (const char*)(wsf + W2F_OFF);
    long bfrag[9];
#pragma unroll
    for (int c = 0; c < 9; ++c)
        bfrag[c] = *reinterpret_cast<const long*>(w2fr + lane * 72 + c * 8);

    int offB[8];                 // per-lane in_bs element offsets for A gather
#pragma unroll
    for (int e = 0; e < 8; ++e) {
        int k = g * 8 + e;
        if (k < 27) {
            int ic = k / 9, r2 = k - ic * 9, ky = r2 / 3, kx = r2 - ky * 3;
            offB[e] = ic * 400 + ky * 20 + kx;
        } else offB[e] = 0;
    }
    const float b1_e = b1f[2 * ocl], b1_o = b1f[2 * ocl + 1];
    float b2v[4], w3v[4];
#pragma unroll
    for (int r = 0; r < 4; ++r) { b2v[r] = b2f[g * 4 + r]; w3v[r] = w3f[g * 4 + r]; }
    const float b3v = b3f[0];

    const float* xin = x + (size_t)img * 3 * 16384;

    // ---- stage 20x20x3 halo as bf16: thread t<240 owns 5 consecutive
    //      elements of LDS row (t>>2); col = (t&3)*5. One div (ic), row-level
    //      bounds; float4+scalar load; packed bf16 writes. ----
    if (tid < 240) {
        int row = tid >> 2;                  // 0..59 = ic*20 + r
        int col = (tid & 3) * 5;             // 0,5,10,15
        int ic  = (row * 13) >> 8;           // row/20 for row<60 (13/256)
        int r   = row - ic * 20;
        int gr  = r0 - 2 + r;
        int gc0 = c0 - 2 + col;
        float v0, v1, v2, v3, v4;
        if (interior || ((unsigned)gr < 128u && gc0 >= 0 && gc0 + 4 < 128)) {
            const float* src = xin + ic * 16384 + gr * 128 + gc0;
            f32x4 q = *reinterpret_cast<const f32x4*>(src);   // 16B-aligned? gc0 may be odd
            v0 = q[0]; v1 = q[1]; v2 = q[2]; v3 = q[3]; v4 = src[4];
        } else {
            const float* srow = xin + ic * 16384 + gr * 128;
            bool rok = (unsigned)gr < 128u;
            v0 = (rok && (unsigned)(gc0 + 0) < 128u) ? srow[gc0 + 0] : 0.f;
            v1 = (rok && (unsigned)(gc0 + 1) < 128u) ? srow[gc0 + 1] : 0.f;
            v2 = (rok && (unsigned)(gc0 + 2) < 128u) ? srow[gc0 + 2] : 0.f;
            v3 = (rok && (unsigned)(gc0 + 3) < 128u) ? srow[gc0 + 3] : 0.f;
            v4 = (rok && (unsigned)(gc0 + 4) < 128u) ? srow[gc0 + 4] : 0.f;
        }
        unsigned short* dst = &in_bs[row * 20 + col];
        if ((col & 1) == 0) {
            *reinterpret_cast<unsigned*>(dst)     = pack_bf2(v0, v1);
            *reinterpret_cast<unsigned*>(dst + 2) = pack_bf2(v2, v3);
            dst[4] = f2bf(v4);
        } else {
            dst[0] = f2bf(v0);
            *reinterpret_cast<unsigned*>(dst + 1) = pack_bf2(v1, v2);
            *reinterpret_cast<unsigned*>(dst + 3) = pack_bf2(v3, v4);
        }
    }
    __syncthreads();

    // ---- conv1 MFMA: groups grp = wid + gi*4; gi<5 unchecked, gi=5 checked
#pragma unroll
    for (int gi = 0; gi < 6; ++gi) {
        const int grp = wid + gi * 4;
        if (gi == 5 && grp != 20) break;      // only wid==0 runs grp 20
        int pos = grp * 16 + ocl;             // A row
        int hy = pos / 18, hx = pos - hy * 18;
        int base = hy * 20 + hx;
        base = base > 357 ? 357 : base;       // clamp tail-group lanes
        bf16x8 afrag;
#pragma unroll
        for (int e = 0; e < 8; ++e)
            afrag[e] = (short)in_bs[base + offB[e]];
        f32x4 d0 = {0.f, 0.f, 0.f, 0.f}, d1 = {0.f, 0.f, 0.f, 0.f};
        d0 = __builtin_amdgcn_mfma_f32_16x16x32_bf16(afrag, c1b0, d0, 0, 0, 0);
        d1 = __builtin_amdgcn_mfma_f32_16x16x32_bf16(afrag, c1b1, d1, 0, 0, 0);
        int p0 = grp * 16 + g * 4;
        if (interior) {
#pragma unroll
            for (int r = 0; r < 4; ++r) {
                int p2 = p0 + r;
                if (gi < 5 || p2 < 324) {
                    int pk = __builtin_amdgcn_cvt_pk_fp8_f32(
                        fmaxf(d0[r] + b1_e, 0.f), fmaxf(d1[r] + b1_o, 0.f), 0, false);
                    *reinterpret_cast<unsigned short*>(&h1_s[p2 * 32 + 2 * ocl]) =
                        (unsigned short)pk;
                }
            }
        } else {
            int hy2 = p0 / 18, hx2 = p0 - hy2 * 18;
#pragma unroll
            for (int r = 0; r < 4; ++r) {
                int p2 = p0 + r;
                if (gi < 5 || p2 < 324) {
                    bool valid = ((unsigned)(r0 - 1 + hy2) < 128u) &&
                                 ((unsigned)(c0 - 1 + hx2) < 128u);
                    float he = valid ? fmaxf(d0[r] + b1_e, 0.f) : 0.f;
                    float ho = valid ? fmaxf(d1[r] + b1_o, 0.f) : 0.f;
                    int pk = __builtin_amdgcn_cvt_pk_fp8_f32(he, ho, 0, false);
                    *reinterpret_cast<unsigned short*>(&h1_s[p2 * 32 + 2 * ocl]) =
                        (unsigned short)pk;
                }
                ++hx2;
                if (hx2 == 18) { hx2 = 0; ++hy2; }
            }
        }
    }
    __syncthreads();

    // ---- conv2 FP8 MFMA (A=w2, B=h1; row-reuse, per-q order fixed) ----
    const unsigned char* hb = &h1_s[((wid * 4) * 18 + ocl) * 32 + g * 8];
    f32x4 acc4[4];
#pragma unroll
    for (int q = 0; q < 4; ++q) acc4[q] = (f32x4){0.f, 0.f, 0.f, 0.f};
#pragma unroll
    for (int rp = 0; rp < 6; ++rp) {
        long fr0 = *reinterpret_cast<const long*>(hb + (rp * 18 + 0) * 32);
        long fr1 = *reinterpret_cast<const long*>(hb + (rp * 18 + 1) * 32);
        long fr2 = *reinterpret_cast<const long*>(hb + (rp * 18 + 2) * 32);
#pragma unroll
        for (int ky = 0; ky < 3; ++ky) {
            const int q = rp - ky;
            if (q >= 0 && q < 4) {
                acc4[q] = __builtin_amdgcn_mfma_f32_16x16x32_fp8_fp8(
                    bfrag[ky * 3 + 0], fr0, acc4[q], 0, 0, 0);
                acc4[q] = __builtin_amdgcn_mfma_f32_16x16x32_fp8_fp8(
                    bfrag[ky * 3 + 1], fr1, acc4[q], 0, 0, 0);
                acc4[q] = __builtin_amdgcn_mfma_f32_16x16x32_fp8_fp8(
                    bfrag[ky * 3 + 2], fr2, acc4[q], 0, 0, 0);
            }
        }
    }
    // conv3: lane holds P[oc=g*4+r][x=ocl]; 4 in-lane FMA + 2 shfl
    float s0 = 0.f, s1 = 0.f, s2 = 0.f, sm = 0.f;
#pragma unroll
    for (int q = 0; q < 4; ++q) {
        const int s = wid * 4 + q;
        float part3 = 0.f;
#pragma unroll
        for (int r = 0; r < 4; ++r)
            part3 = fmaf(fmaxf(acc4[q][r] + b2v[r], 0.f), w3v[r], part3);
        part3 += __shfl_xor(part3, 16);
        part3 += __shfl_xor(part3, 32);
        if (lane < 16) {
            int xw = lane;
            float msk = 1.f / (1.f + __expf(-(part3 + b3v)));
            out[776 + (size_t)img * 16384 + (size_t)(r0 + s) * 128 + (c0 + xw)] = msk;
            float f0  = bf2f(in_bs[      (s + 2) * 20 + (xw + 2)]);
            float f1v = bf2f(in_bs[400 + (s + 2) * 20 + (xw + 2)]);
            float f2v = bf2f(in_bs[800 + (s + 2) * 20 + (xw + 2)]);
            s0 = fmaf(msk, f0, s0);
            s1 = fmaf(msk, f1v, s1);
            s2 = fmaf(msk, f2v, s2);
            sm += msk;
        }
    }

    // ---- block reduction of the 4 sums ----
#pragma unroll
    for (int off = 32; off > 0; off >>= 1) {
        s0 += __shfl_down(s0, off);
        s1 += __shfl_down(s1, off);
        s2 += __shfl_down(s2, off);
        sm += __shfl_down(sm, off);
    }
    if (lane == 0) { red[wid][0] = s0; red[wid][1] = s1; red[wid][2] = s2; red[wid][3] = sm; }
    __syncthreads();
    if (tid < 4) {
        float s = red[0][tid] + red[1][tid] + red[2][tid] + red[3][tid];
        colsum[(size_t)blockIdx.x * 4 + tid] = s;   // [img*64+tile][4]
    }
}

// Tail: 1024 threads; ta2/ta3 vectorized (b128 + lane-shfl conv halo).
__global__ __launch_bounds__(1024) void tail_kernel(
    const float* __restrict__ colsum,
    const float* __restrict__ cw1, const float* __restrict__ cb1,
    const float* __restrict__ cw2, const float* __restrict__ cb2,
    const float* __restrict__ cw3, const float* __restrict__ cb3,
    const float* __restrict__ tw1, const float* __restrict__ tb1,
    const float* __restrict__ tw2, const float* __restrict__ tb2,
    const float* __restrict__ tw3, const float* __restrict__ tb3,
    const float* __restrict__ fw1, const float* __restrict__ fb1,
    const float* __restrict__ fw2, const float* __restrict__ fb2,
    const float* __restrict__ fw3, const float* __restrict__ fb3,
    float* __restrict__ out)
{
    const int b = blockIdx.x, tid = threadIdx.x;
    __shared__ float tmp[64][4];
    __shared__ float cs_s[3 * 64];
    __shared__ float e3s[3 * 64];
    __shared__ __align__(16) float f1[32 * 64];
    __shared__ __align__(16) float f2[64 * 64];
    __shared__ __align__(16) float tf[32 * 64];
    __shared__ float pooled[32], g1[64], g2[32], sca[8];

    if (tid < 256) {
        int t = tid >> 2, slot = tid & 3;
        const float* pp = colsum + (size_t)((b * 64 + t) * 64) * 4 + slot;
        float s = 0.f;
#pragma unroll
        for (int tl = 0; tl < 64; ++tl) s += pp[tl * 4];
        tmp[t][slot] = s;
    }
    __syncthreads();
    if (tid < 192) {
        int c = tid >> 6, t = tid & 63;
        float v = tmp[t][c] / (tmp[t][3] + 1e-8f);
        cs_s[tid] = v;
        out[8 + (b * 64 + t) * 3 + c] = v;
    }
    __syncthreads();

    if (tid < 64) {
        int t = tid;
        float c0v = cs_s[t], c1v = cs_s[64 + t], c2v = cs_s[128 + t];
        float e1[16];
#pragma unroll
        for (int o = 0; o < 16; ++o)
            e1[o] = fmaxf(cb1[o] + cw1[o * 3 + 0] * c0v + cw1[o * 3 + 1] * c1v
                                 + cw1[o * 3 + 2] * c2v, 0.f);
        float e2[8];
#pragma unroll
        for (int o = 0; o < 8; ++o) {
            float a = cb2[o];
#pragma unroll
            for (int i2 = 0; i2 < 16; ++i2) a += cw2[o * 16 + i2] * e1[i2];
            e2[o] = fmaxf(a, 0.f);
        }
#pragma unroll
        for (int o = 0; o < 3; ++o) {
            float a = cb3[o];
#pragma unroll
            for (int i2 = 0; i2 < 8; ++i2) a += cw3[o * 8 + i2] * e2[i2];
            e3s[o * 64 + t] = a;   // no relu on last ct conv
        }
    }
    __syncthreads();

    // ta1: 3->32 k3 p1
    {
        int o = tid >> 6, t = tid & 63;
#pragma unroll
        for (int h = 0; h < 2; ++h) {
            int oo = o + 16 * h;
            float a = tb1[oo];
#pragma unroll
            for (int ic = 0; ic < 3; ++ic)
#pragma unroll
                for (int k = 0; k < 3; ++k) {
                    int ttk = t + k - 1;
                    if ((unsigned)ttk < 64u)
                        a += e3s[ic * 64 + ttk] * tw1[(oo * 3 + ic) * 3 + k];
                }
            f1[oo * 64 + t] = fmaxf(a, 0.f);
        }
    }
    __syncthreads();

    // ta2: 32->64 k3 p1 — thread (oo=tid>>4, t4=tid&15) computes t=4t4..4t4+3
    {
        int oo = tid >> 4, t4 = tid & 15;
        float a0 = tb2[oo], a1 = a0, a2 = a0, a3 = a0;
        for (int ic = 0; ic < 32; ++ic) {
            f32x4 c = *reinterpret_cast<const f32x4*>(&f1[ic * 64 + t4 * 4]);
            float pm = __shfl_up(c[3], 1);
            float pp = __shfl_down(c[0], 1);
            if (t4 == 0)  pm = 0.f;          // t-1 < 0 pad
            if (t4 == 15) pp = 0.f;          // t+1 > 63 pad
            const float* wp = tw2 + (oo * 32 + ic) * 3;
            float w0 = wp[0], w1 = wp[1], w2 = wp[2];
            a0 = fmaf(w0, pm,   fmaf(w1, c[0], fmaf(w2, c[1], a0)));
            a1 = fmaf(w0, c[0], fmaf(w1, c[1], fmaf(w2, c[2], a1)));
            a2 = fmaf(w0, c[1], fmaf(w1, c[2], fmaf(w2, c[3], a2)));
            a3 = fmaf(w0, c[2], fmaf(w1, c[3], fmaf(w2, pp,   a3)));
        }
        f32x4 r = {fmaxf(a0, 0.f), fmaxf(a1, 0.f), fmaxf(a2, 0.f), fmaxf(a3, 0.f)};
        *reinterpret_cast<f32x4*>(&f2[oo * 64 + t4 * 4]) = r;
    }
    __syncthreads();

    // ta3: 64->32 k3 p1 (+ temporal_features out), threads 0..511
    if (tid < 512) {
        int oo = tid >> 4, t4 = tid & 15;
        float a0 = tb3[oo], a1 = a0, a2 = a0, a3 = a0;
        for (int ic = 0; ic < 64; ++ic) {
            f32x4 c = *reinterpret_cast<const f32x4*>(&f2[ic * 64 + t4 * 4]);
            float pm = __shfl_up(c[3], 1);
            float pp = __shfl_down(c[0], 1);
            if (t4 == 0)  pm = 0.f;
            if (t4 == 15) pp = 0.f;
            const float* wp = tw3 + (oo * 64 + ic) * 3;
            float w0 = wp[0], w1 = wp[1], w2 = wp[2];
            a0 = fmaf(w0, pm,   fmaf(w1, c[0], fmaf(w2, c[1], a0)));
            a1 = fmaf(w0, c[0], fmaf(w1, c[1], fmaf(w2, c[2], a1)));
            a2 = fmaf(w0, c[1], fmaf(w1, c[2], fmaf(w2, c[3], a2)));
            a3 = fmaf(w0, c[2], fmaf(w1, c[3], fmaf(w2, pp,   a3)));
        }
        f32x4 r = {fmaxf(a0, 0.f), fmaxf(a1, 0.f), fmaxf(a2, 0.f), fmaxf(a3, 0.f)};
        *reinterpret_cast<f32x4*>(&tf[oo * 64 + t4 * 4]) = r;
        *reinterpret_cast<f32x4*>(&out[TF_OFF + (b * 32 + oo) * 64 + t4 * 4]) = r;
    }
    __syncthreads();

    if (tid < 32) {
        float s = 0.f;
#pragma unroll
        for (int t4 = 0; t4 < 16; ++t4) {
            f32x4 c = *reinterpret_cast<const f32x4*>(&tf[tid * 64 + t4 * 4]);
            s += c[0] + c[1] + c[2] + c[3];
        }
        pooled[tid] = s * (1.f / 64.f);
    }
    __syncthreads();

    if (tid < 64) {
        float a = fb1[tid];
#pragma unroll
        for (int i2 = 0; i2 < 32; ++i2) a += pooled[i2] * fw1[tid * 32 + i2];
        g1[tid] = fmaxf(a, 0.f);
    }
    __syncthreads();
    if (tid < 32) {
        float a = fb2[tid];
        for (int i2 = 0; i2 < 64; ++i2) a += g1[i2] * fw2[tid * 64 + i2];
        g2[tid] = fmaxf(a, 0.f);
    }
    __syncthreads();
    if (tid == 0) {
        float a = fb3[0];
        for (int i2 = 0; i2 < 32; ++i2) a += g2[i2] * fw3[i2];
        float flow = 1.f / (1.f + expf(-a));
        sca[0] = flow;
        out[b] = flow;
    }
    if (tid >= 4 && tid < 7) {
        int c = tid - 4;
        float mu = 0.f;
        for (int t = 0; t < 64; ++t) mu += cs_s[c * 64 + t];
        mu *= (1.f / 64.f);
        float v = 0.f;
        for (int t = 0; t < 64; ++t) { float d = cs_s[c * 64 + t] - mu; v += d * d; }
        sca[1 + c] = sqrtf(v / 63.f);
    }
    __syncthreads();
    if (tid == 0) {
        float s0 = sca[1], s1 = sca[2], s2 = sca[3];
        float mu = (s0 + s1 + s2) * (1.f / 3.f);
        float var = ((s0 - mu) * (s0 - mu) + (s1 - mu) * (s1 - mu) + (s2 - mu) * (s2 - mu)) * 0.5f;
        float sy = 1.f / (1.f + expf(var));     // sigmoid(-var)
        out[4 + b] = sy;
        out[NAT_OFF + b] = (sca[0] + sy) * 0.5f;
    }
}

extern "C" void kernel_launch(void* const* d_in, const int* in_sizes, int n_in,
                              void* d_out, int out_size, void* d_ws, size_t ws_size,
                              hipStream_t stream)
{
    float* wsf = (float*)d_ws;
    float* out = (float*)d_out;

    prep_kernel<<<1, 64, 0, stream>>>(
        (const float*)d_in[1], (const float*)d_in[3], wsf);

    seg_kernel<<<dim3(16384), 256, 0, stream>>>((const float*)d_in[0],
        (const float*)d_in[2], (const float*)d_in[4],
        (const float*)d_in[5], (const float*)d_in[6],
        wsf, wsf, out);

    tail_kernel<<<dim3(4), 1024, 0, stream>>>(wsf,
        (const float*)d_in[7],  (const float*)d_in[8],
        (const float*)d_in[9],  (const float*)d_in[10],
        (const float*)d_in[11], (const float*)d_in[12],
        (const float*)d_in[13], (const float*)d_in[14],
        (const float*)d_in[15], (const float*)d_in[16],
        (const float*)d_in[17], (const float*)d_in[18],
        (const float*)d_in[19], (const float*)d_in[20],
        (const float*)d_in[21], (const float*)d_in[22],
        (const float*)d_in[23], (const float*)d_in[24],
        out);
}

// Round 21
// 133.684 us; speedup vs baseline: 3.4656x; 1.0949x over previous
//
#include <hip/hip_runtime.h>
#include <hip/hip_bf16.h>

// BloodFlowSkinAnalyzer — f32 in/out (verified r5). Out layout (floats):
//   flow[4]@0, sync[4]@4, color[4*64*3]@8, masks[4,64,1,128,128]@776,
//   naturalness[4]@4195080, temporal[4,32,64]@4195084
// conv1 bf16 MFMA + conv2 FP8 e4m3 MFMA (layouts/numerics HW-verified r7-r20).
// r21: r20 + h1 row stride 32B -> 40B. 32B rows alias banks every 4 rows:
//      conv1 writes (g-groups 4 rows apart) were 8-way conflicted, conv2
//      b64 reads ~4-way (SQ_LDS_BANK_CONFLICT 2.07e7 = ~27% of block cycles).
//      40B stride: rows advance 10 banks mod 32 -> reads conflict-free,
//      writes in disjoint windows. Addressing-only change; absmax identical.
// ws (floats): colsum[16384][4] @0 | w1frag @65536 | w2frag @66560.

typedef __attribute__((ext_vector_type(8))) short bf16x8;
typedef __attribute__((ext_vector_type(4))) float f32x4;

#define NAT_OFF  4195080
#define TF_OFF   4195084
#define W1F_OFF  65536
#define W2F_OFF  66560

__device__ __forceinline__ unsigned short f2bf(float f) {   // RNE f32->bf16
    unsigned u = __float_as_uint(f);
    u += 0x7FFFu + ((u >> 16) & 1u);
    return (unsigned short)(u >> 16);
}
__device__ __forceinline__ float bf2f(unsigned short u) {
    return __uint_as_float((unsigned)u << 16);
}
__device__ __forceinline__ unsigned pack_bf2(float lo, float hi) {
    __hip_bfloat162 h2 = __float22bfloat162_rn(make_float2(lo, hi));
    return *reinterpret_cast<unsigned*>(&h2);   // .x low 16 bits (RNE = f2bf)
}

// Pre-bake per-lane-class (class = lane = g*16+ocl) MFMA fragments into ws.
__global__ __launch_bounds__(64) void prep_kernel(
    const float* __restrict__ w1f, const float* __restrict__ w2f,
    float* __restrict__ wsf)
{
    const int L = threadIdx.x;           // lane class 0..63
    const int ocl = L & 15, g = L >> 4;
    unsigned short* w1fr = (unsigned short*)(wsf + W1F_OFF);
#pragma unroll
    for (int e = 0; e < 8; ++e) {
        int k = g * 8 + e;
        unsigned short v0 = 0, v1 = 0;
        if (k < 27) {
            v0 = f2bf(w1f[(2 * ocl)     * 27 + k]);
            v1 = f2bf(w1f[(2 * ocl + 1) * 27 + k]);
        }
        w1fr[L * 16 + e]     = v0;
        w1fr[L * 16 + 8 + e] = v1;
    }
    char* w2fr = (char*)(wsf + W2F_OFF);
#pragma unroll
    for (int c = 0; c < 9; ++c) {
        float w[8];
#pragma unroll
        for (int e = 0; e < 8; ++e)
            w[e] = w2f[(ocl * 32 + g * 8 + e) * 9 + c];
        int lo = __builtin_amdgcn_cvt_pk_fp8_f32(w[0], w[1], 0, false);
        lo     = __builtin_amdgcn_cvt_pk_fp8_f32(w[2], w[3], lo, true);
        int hi = __builtin_amdgcn_cvt_pk_fp8_f32(w[4], w[5], 0, false);
        hi     = __builtin_amdgcn_cvt_pk_fp8_f32(w[6], w[7], hi, true);
        long v = (long)(unsigned)lo | ((long)hi << 32);
        *reinterpret_cast<long*>(w2fr + L * 72 + c * 8) = v;
    }
}

// Fused seg: one 16x16 tile per block. stage -> conv1 bf16 MFMA -> conv2 fp8
// MFMA -> conv3 epilogue + masked sums. 2 barriers per block.
__global__ __launch_bounds__(256) void seg_kernel(
    const float* __restrict__ x,
    const float* __restrict__ b1f, const float* __restrict__ b2f,
    const float* __restrict__ w3f, const float* __restrict__ b3f,
    const float* __restrict__ wsf,
    float* __restrict__ colsum, float* __restrict__ out)
{
    const int tid  = threadIdx.x;
    const int lane = tid & 63;
    const int wid  = tid >> 6;
    const int img  = blockIdx.x >> 6;        // b*64+t
    const int tile = blockIdx.x & 63;
    const int r0 = (tile >> 3) * 16, c0 = (tile & 7) * 16;
    const bool interior = (r0 >= 16 && r0 <= 96 && c0 >= 16 && c0 <= 96);

    __shared__ __align__(4)  unsigned short in_bs[1200];  // 3x20x20 bf16 halo
    __shared__ __align__(16) unsigned char h1_s[12960];   // [(y*18+x)*40+oc] fp8
    __shared__ float red[4][4];

    const int ocl = lane & 15;   // free idx
    const int g   = lane >> 4;   // k-group (8 k's each)

    // ---- fragments from ws (prep-baked; lane == class) ----
    const unsigned short* w1fr = (const unsigned short*)(wsf + W1F_OFF);
    bf16x8 c1b0 = *reinterpret_cast<const bf16x8*>(&w1fr[lane * 16]);
    bf16x8 c1b1 = *reinterpret_cast<const bf16x8*>(&w1fr[lane * 16 + 8]);
    const char* w2fr = (const char*)(wsf + W2F_OFF);
    long bfrag[9];
#pragma unroll
    for (int c = 0; c < 9; ++c)
        bfrag[c] = *reinterpret_cast<const long*>(w2fr + lane * 72 + c * 8);

    int offB[8];                 // per-lane in_bs element offsets for A gather
#pragma unroll
    for (int e = 0; e < 8; ++e) {
        int k = g * 8 + e;
        if (k < 27) {
            int ic = k / 9, r2 = k - ic * 9, ky = r2 / 3, kx = r2 - ky * 3;
            offB[e] = ic * 400 + ky * 20 + kx;
        } else offB[e] = 0;
    }
    const float b1_e = b1f[2 * ocl], b1_o = b1f[2 * ocl + 1];
    float b2v[4], w3v[4];
#pragma unroll
    for (int r = 0; r < 4; ++r) { b2v[r] = b2f[g * 4 + r]; w3v[r] = w3f[g * 4 + r]; }
    const float b3v = b3f[0];

    const float* xin = x + (size_t)img * 3 * 16384;

    // ---- stage 20x20x3 halo as bf16: thread t<240 owns 5 consecutive
    //      elements of LDS row (t>>2); col = (t&3)*5. ----
    if (tid < 240) {
        int row = tid >> 2;                  // 0..59 = ic*20 + r
        int col = (tid & 3) * 5;             // 0,5,10,15
        int ic  = (row * 13) >> 8;           // row/20 for row<60
        int r   = row - ic * 20;
        int gr  = r0 - 2 + r;
        int gc0 = c0 - 2 + col;
        float v0, v1, v2, v3, v4;
        if (interior || ((unsigned)gr < 128u && gc0 >= 0 && gc0 + 4 < 128)) {
            const float* src = xin + ic * 16384 + gr * 128 + gc0;
            f32x4 q = *reinterpret_cast<const f32x4*>(src);
            v0 = q[0]; v1 = q[1]; v2 = q[2]; v3 = q[3]; v4 = src[4];
        } else {
            const float* srow = xin + ic * 16384 + gr * 128;
            bool rok = (unsigned)gr < 128u;
            v0 = (rok && (unsigned)(gc0 + 0) < 128u) ? srow[gc0 + 0] : 0.f;
            v1 = (rok && (unsigned)(gc0 + 1) < 128u) ? srow[gc0 + 1] : 0.f;
            v2 = (rok && (unsigned)(gc0 + 2) < 128u) ? srow[gc0 + 2] : 0.f;
            v3 = (rok && (unsigned)(gc0 + 3) < 128u) ? srow[gc0 + 3] : 0.f;
            v4 = (rok && (unsigned)(gc0 + 4) < 128u) ? srow[gc0 + 4] : 0.f;
        }
        unsigned short* dst = &in_bs[row * 20 + col];
        if ((col & 1) == 0) {
            *reinterpret_cast<unsigned*>(dst)     = pack_bf2(v0, v1);
            *reinterpret_cast<unsigned*>(dst + 2) = pack_bf2(v2, v3);
            dst[4] = f2bf(v4);
        } else {
            dst[0] = f2bf(v0);
            *reinterpret_cast<unsigned*>(dst + 1) = pack_bf2(v1, v2);
            *reinterpret_cast<unsigned*>(dst + 3) = pack_bf2(v3, v4);
        }
    }
    __syncthreads();

    // ---- conv1 MFMA: groups grp = wid + gi*4; gi<5 unchecked, gi=5 checked
#pragma unroll
    for (int gi = 0; gi < 6; ++gi) {
        const int grp = wid + gi * 4;
        if (gi == 5 && grp != 20) break;      // only wid==0 runs grp 20
        int pos = grp * 16 + ocl;             // A row
        int hy = pos / 18, hx = pos - hy * 18;
        int base = hy * 20 + hx;
        base = base > 357 ? 357 : base;       // clamp tail-group lanes
        bf16x8 afrag;
#pragma unroll
        for (int e = 0; e < 8; ++e)
            afrag[e] = (short)in_bs[base + offB[e]];
        f32x4 d0 = {0.f, 0.f, 0.f, 0.f}, d1 = {0.f, 0.f, 0.f, 0.f};
        d0 = __builtin_amdgcn_mfma_f32_16x16x32_bf16(afrag, c1b0, d0, 0, 0, 0);
        d1 = __builtin_amdgcn_mfma_f32_16x16x32_bf16(afrag, c1b1, d1, 0, 0, 0);
        int p0 = grp * 16 + g * 4;
        if (interior) {
#pragma unroll
            for (int r = 0; r < 4; ++r) {
                int p2 = p0 + r;
                if (gi < 5 || p2 < 324) {
                    int pk = __builtin_amdgcn_cvt_pk_fp8_f32(
                        fmaxf(d0[r] + b1_e, 0.f), fmaxf(d1[r] + b1_o, 0.f), 0, false);
                    *reinterpret_cast<unsigned short*>(&h1_s[p2 * 40 + 2 * ocl]) =
                        (unsigned short)pk;
                }
            }
        } else {
            int hy2 = p0 / 18, hx2 = p0 - hy2 * 18;
#pragma unroll
            for (int r = 0; r < 4; ++r) {
                int p2 = p0 + r;
                if (gi < 5 || p2 < 324) {
                    bool valid = ((unsigned)(r0 - 1 + hy2) < 128u) &&
                                 ((unsigned)(c0 - 1 + hx2) < 128u);
                    float he = valid ? fmaxf(d0[r] + b1_e, 0.f) : 0.f;
                    float ho = valid ? fmaxf(d1[r] + b1_o, 0.f) : 0.f;
                    int pk = __builtin_amdgcn_cvt_pk_fp8_f32(he, ho, 0, false);
                    *reinterpret_cast<unsigned short*>(&h1_s[p2 * 40 + 2 * ocl]) =
                        (unsigned short)pk;
                }
                ++hx2;
                if (hx2 == 18) { hx2 = 0; ++hy2; }
            }
        }
    }
    __syncthreads();

    // ---- conv2 FP8 MFMA (A=w2, B=h1; row-reuse, per-q order fixed) ----
    const unsigned char* hb = &h1_s[((wid * 4) * 18 + ocl) * 40 + g * 8];
    f32x4 acc4[4];
#pragma unroll
    for (int q = 0; q < 4; ++q) acc4[q] = (f32x4){0.f, 0.f, 0.f, 0.f};
#pragma unroll
    for (int rp = 0; rp < 6; ++rp) {
        long fr0 = *reinterpret_cast<const long*>(hb + (rp * 18 + 0) * 40);
        long fr1 = *reinterpret_cast<const long*>(hb + (rp * 18 + 1) * 40);
        long fr2 = *reinterpret_cast<const long*>(hb + (rp * 18 + 2) * 40);
#pragma unroll
        for (int ky = 0; ky < 3; ++ky) {
            const int q = rp - ky;
            if (q >= 0 && q < 4) {
                acc4[q] = __builtin_amdgcn_mfma_f32_16x16x32_fp8_fp8(
                    bfrag[ky * 3 + 0], fr0, acc4[q], 0, 0, 0);
                acc4[q] = __builtin_amdgcn_mfma_f32_16x16x32_fp8_fp8(
                    bfrag[ky * 3 + 1], fr1, acc4[q], 0, 0, 0);
                acc4[q] = __builtin_amdgcn_mfma_f32_16x16x32_fp8_fp8(
                    bfrag[ky * 3 + 2], fr2, acc4[q], 0, 0, 0);
            }
        }
    }
    // conv3: lane holds P[oc=g*4+r][x=ocl]; 4 in-lane FMA + 2 shfl
    float s0 = 0.f, s1 = 0.f, s2 = 0.f, sm = 0.f;
#pragma unroll
    for (int q = 0; q < 4; ++q) {
        const int s = wid * 4 + q;
        float part3 = 0.f;
#pragma unroll
        for (int r = 0; r < 4; ++r)
            part3 = fmaf(fmaxf(acc4[q][r] + b2v[r], 0.f), w3v[r], part3);
        part3 += __shfl_xor(part3, 16);
        part3 += __shfl_xor(part3, 32);
        if (lane < 16) {
            int xw = lane;
            float msk = 1.f / (1.f + __expf(-(part3 + b3v)));
            out[776 + (size_t)img * 16384 + (size_t)(r0 + s) * 128 + (c0 + xw)] = msk;
            float f0  = bf2f(in_bs[      (s + 2) * 20 + (xw + 2)]);
            float f1v = bf2f(in_bs[400 + (s + 2) * 20 + (xw + 2)]);
            float f2v = bf2f(in_bs[800 + (s + 2) * 20 + (xw + 2)]);
            s0 = fmaf(msk, f0, s0);
            s1 = fmaf(msk, f1v, s1);
            s2 = fmaf(msk, f2v, s2);
            sm += msk;
        }
    }

    // ---- block reduction of the 4 sums ----
#pragma unroll
    for (int off = 32; off > 0; off >>= 1) {
        s0 += __shfl_down(s0, off);
        s1 += __shfl_down(s1, off);
        s2 += __shfl_down(s2, off);
        sm += __shfl_down(sm, off);
    }
    if (lane == 0) { red[wid][0] = s0; red[wid][1] = s1; red[wid][2] = s2; red[wid][3] = sm; }
    __syncthreads();
    if (tid < 4) {
        float s = red[0][tid] + red[1][tid] + red[2][tid] + red[3][tid];
        colsum[(size_t)blockIdx.x * 4 + tid] = s;   // [img*64+tile][4]
    }
}

// Tail: 1024 threads; ta2/ta3 vectorized (b128 + lane-shfl conv halo).
__global__ __launch_bounds__(1024) void tail_kernel(
    const float* __restrict__ colsum,
    const float* __restrict__ cw1, const float* __restrict__ cb1,
    const float* __restrict__ cw2, const float* __restrict__ cb2,
    const float* __restrict__ cw3, const float* __restrict__ cb3,
    const float* __restrict__ tw1, const float* __restrict__ tb1,
    const float* __restrict__ tw2, const float* __restrict__ tb2,
    const float* __restrict__ tw3, const float* __restrict__ tb3,
    const float* __restrict__ fw1, const float* __restrict__ fb1,
    const float* __restrict__ fw2, const float* __restrict__ fb2,
    const float* __restrict__ fw3, const float* __restrict__ fb3,
    float* __restrict__ out)
{
    const int b = blockIdx.x, tid = threadIdx.x;
    __shared__ float tmp[64][4];
    __shared__ float cs_s[3 * 64];
    __shared__ float e3s[3 * 64];
    __shared__ __align__(16) float f1[32 * 64];
    __shared__ __align__(16) float f2[64 * 64];
    __shared__ __align__(16) float tf[32 * 64];
    __shared__ float pooled[32], g1[64], g2[32], sca[8];

    if (tid < 256) {
        int t = tid >> 2, slot = tid & 3;
        const float* pp = colsum + (size_t)((b * 64 + t) * 64) * 4 + slot;
        float s = 0.f;
#pragma unroll
        for (int tl = 0; tl < 64; ++tl) s += pp[tl * 4];
        tmp[t][slot] = s;
    }
    __syncthreads();
    if (tid < 192) {
        int c = tid >> 6, t = tid & 63;
        float v = tmp[t][c] / (tmp[t][3] + 1e-8f);
        cs_s[tid] = v;
        out[8 + (b * 64 + t) * 3 + c] = v;
    }
    __syncthreads();

    if (tid < 64) {
        int t = tid;
        float c0v = cs_s[t], c1v = cs_s[64 + t], c2v = cs_s[128 + t];
        float e1[16];
#pragma unroll
        for (int o = 0; o < 16; ++o)
            e1[o] = fmaxf(cb1[o] + cw1[o * 3 + 0] * c0v + cw1[o * 3 + 1] * c1v
                                 + cw1[o * 3 + 2] * c2v, 0.f);
        float e2[8];
#pragma unroll
        for (int o = 0; o < 8; ++o) {
            float a = cb2[o];
#pragma unroll
            for (int i2 = 0; i2 < 16; ++i2) a += cw2[o * 16 + i2] * e1[i2];
            e2[o] = fmaxf(a, 0.f);
        }
#pragma unroll
        for (int o = 0; o < 3; ++o) {
            float a = cb3[o];
#pragma unroll
            for (int i2 = 0; i2 < 8; ++i2) a += cw3[o * 8 + i2] * e2[i2];
            e3s[o * 64 + t] = a;   // no relu on last ct conv
        }
    }
    __syncthreads();

    // ta1: 3->32 k3 p1
    {
        int o = tid >> 6, t = tid & 63;
#pragma unroll
        for (int h = 0; h < 2; ++h) {
            int oo = o + 16 * h;
            float a = tb1[oo];
#pragma unroll
            for (int ic = 0; ic < 3; ++ic)
#pragma unroll
                for (int k = 0; k < 3; ++k) {
                    int ttk = t + k - 1;
                    if ((unsigned)ttk < 64u)
                        a += e3s[ic * 64 + ttk] * tw1[(oo * 3 + ic) * 3 + k];
                }
            f1[oo * 64 + t] = fmaxf(a, 0.f);
        }
    }
    __syncthreads();

    // ta2: 32->64 k3 p1 — thread (oo=tid>>4, t4=tid&15) computes t=4t4..4t4+3
    {
        int oo = tid >> 4, t4 = tid & 15;
        float a0 = tb2[oo], a1 = a0, a2 = a0, a3 = a0;
        for (int ic = 0; ic < 32; ++ic) {
            f32x4 c = *reinterpret_cast<const f32x4*>(&f1[ic * 64 + t4 * 4]);
            float pm = __shfl_up(c[3], 1);
            float pp = __shfl_down(c[0], 1);
            if (t4 == 0)  pm = 0.f;          // t-1 < 0 pad
            if (t4 == 15) pp = 0.f;          // t+1 > 63 pad
            const float* wp = tw2 + (oo * 32 + ic) * 3;
            float w0 = wp[0], w1 = wp[1], w2 = wp[2];
            a0 = fmaf(w0, pm,   fmaf(w1, c[0], fmaf(w2, c[1], a0)));
            a1 = fmaf(w0, c[0], fmaf(w1, c[1], fmaf(w2, c[2], a1)));
            a2 = fmaf(w0, c[1], fmaf(w1, c[2], fmaf(w2, c[3], a2)));
            a3 = fmaf(w0, c[2], fmaf(w1, c[3], fmaf(w2, pp,   a3)));
        }
        f32x4 r = {fmaxf(a0, 0.f), fmaxf(a1, 0.f), fmaxf(a2, 0.f), fmaxf(a3, 0.f)};
        *reinterpret_cast<f32x4*>(&f2[oo * 64 + t4 * 4]) = r;
    }
    __syncthreads();

    // ta3: 64->32 k3 p1 (+ temporal_features out), threads 0..511
    if (tid < 512) {
        int oo = tid >> 4, t4 = tid & 15;
        float a0 = tb3[oo], a1 = a0, a2 = a0, a3 = a0;
        for (int ic = 0; ic < 64; ++ic) {
            f32x4 c = *reinterpret_cast<const f32x4*>(&f2[ic * 64 + t4 * 4]);
            float pm = __shfl_up(c[3], 1);
            float pp = __shfl_down(c[0], 1);
            if (t4 == 0)  pm = 0.f;
            if (t4 == 15) pp = 0.f;
            const float* wp = tw3 + (oo * 64 + ic) * 3;
            float w0 = wp[0], w1 = wp[1], w2 = wp[2];
            a0 = fmaf(w0, pm,   fmaf(w1, c[0], fmaf(w2, c[1], a0)));
            a1 = fmaf(w0, c[0], fmaf(w1, c[1], fmaf(w2, c[2], a1)));
            a2 = fmaf(w0, c[1], fmaf(w1, c[2], fmaf(w2, c[3], a2)));
            a3 = fmaf(w0, c[2], fmaf(w1, c[3], fmaf(w2, pp,   a3)));
        }
        f32x4 r = {fmaxf(a0, 0.f), fmaxf(a1, 0.f), fmaxf(a2, 0.f), fmaxf(a3, 0.f)};
        *reinterpret_cast<f32x4*>(&tf[oo * 64 + t4 * 4]) = r;
        *reinterpret_cast<f32x4*>(&out[TF_OFF + (b * 32 + oo) * 64 + t4 * 4]) = r;
    }
    __syncthreads();

    if (tid < 32) {
        float s = 0.f;
#pragma unroll
        for (int t4 = 0; t4 < 16; ++t4) {
            f32x4 c = *reinterpret_cast<const f32x4*>(&tf[tid * 64 + t4 * 4]);
            s += c[0] + c[1] + c[2] + c[3];
        }
        pooled[tid] = s * (1.f / 64.f);
    }
    __syncthreads();

    if (tid < 64) {
        float a = fb1[tid];
#pragma unroll
        for (int i2 = 0; i2 < 32; ++i2) a += pooled[i2] * fw1[tid * 32 + i2];
        g1[tid] = fmaxf(a, 0.f);
    }
    __syncthreads();
    if (tid < 32) {
        float a = fb2[tid];
        for (int i2 = 0; i2 < 64; ++i2) a += g1[i2] * fw2[tid * 64 + i2];
        g2[tid] = fmaxf(a, 0.f);
    }
    __syncthreads();
    if (tid == 0) {
        float a = fb3[0];
        for (int i2 = 0; i2 < 32; ++i2) a += g2[i2] * fw3[i2];
        float flow = 1.f / (1.f + expf(-a));
        sca[0] = flow;
        out[b] = flow;
    }
    if (tid >= 4 && tid < 7) {
        int c = tid - 4;
        float mu = 0.f;
        for (int t = 0; t < 64; ++t) mu += cs_s[c * 64 + t];
        mu *= (1.f / 64.f);
        float v = 0.f;
        for (int t = 0; t < 64; ++t) { float d = cs_s[c * 64 + t] - mu; v += d * d; }
        sca[1 + c] = sqrtf(v / 63.f);
    }
    __syncthreads();
    if (tid == 0) {
        float s0 = sca[1], s1 = sca[2], s2 = sca[3];
        float mu = (s0 + s1 + s2) * (1.f / 3.f);
        float var = ((s0 - mu) * (s0 - mu) + (s1 - mu) * (s1 - mu) + (s2 - mu) * (s2 - mu)) * 0.5f;
        float sy = 1.f / (1.f + expf(var));     // sigmoid(-var)
        out[4 + b] = sy;
        out[NAT_OFF + b] = (sca[0] + sy) * 0.5f;
    }
}

extern "C" void kernel_launch(void* const* d_in, const int* in_sizes, int n_in,
                              void* d_out, int out_size, void* d_ws, size_t ws_size,
                              hipStream_t stream)
{
    float* wsf = (float*)d_ws;
    float* out = (float*)d_out;

    prep_kernel<<<1, 64, 0, stream>>>(
        (const float*)d_in[1], (const float*)d_in[3], wsf);

    seg_kernel<<<dim3(16384), 256, 0, stream>>>((const float*)d_in[0],
        (const float*)d_in[2], (const float*)d_in[4],
        (const float*)d_in[5], (const float*)d_in[6],
        wsf, wsf, out);

    tail_kernel<<<dim3(4), 1024, 0, stream>>>(wsf,
        (const float*)d_in[7],  (const float*)d_in[8],
        (const float*)d_in[9],  (const float*)d_in[10],
        (const float*)d_in[11], (const float*)d_in[12],
        (const float*)d_in[13], (const float*)d_in[14],
        (const float*)d_in[15], (const float*)d_in[16],
        (const float*)d_in[17], (const float*)d_in[18],
        (const float*)d_in[19], (const float*)d_in[20],
        (const float*)d_in[21], (const float*)d_in[22],
        (const float*)d_in[23], (const float*)d_in[24],
        out);
}

// Round 22
// 128.543 us; speedup vs baseline: 3.6042x; 1.0400x over previous
//
#include <hip/hip_runtime.h>
#include <hip/hip_bf16.h>

// BloodFlowSkinAnalyzer — f32 in/out (verified r5). Out layout (floats):
//   flow[4]@0, sync[4]@4, color[4*64*3]@8, masks[4,64,1,128,128]@776,
//   naturalness[4]@4195080, temporal[4,32,64]@4195084
// conv1 bf16 MFMA + conv2 FP8 e4m3 MFMA (layouts/numerics HW-verified r7-r21).
// r22: r21 + all-lane conv3 epilogue (lane-group g handles row q=g; was
//      lane<16 divergent x4 sequential q) + sigmoid via v_rcp_f32.
//      VALUBusy was 85% — this removes ~60-70 divergent wave-instrs/wave.
// ws (floats): colsum[16384][4] @0 | w1frag @65536 | w2frag @66560.

typedef __attribute__((ext_vector_type(8))) short bf16x8;
typedef __attribute__((ext_vector_type(4))) float f32x4;

#define NAT_OFF  4195080
#define TF_OFF   4195084
#define W1F_OFF  65536
#define W2F_OFF  66560

__device__ __forceinline__ unsigned short f2bf(float f) {   // RNE f32->bf16
    unsigned u = __float_as_uint(f);
    u += 0x7FFFu + ((u >> 16) & 1u);
    return (unsigned short)(u >> 16);
}
__device__ __forceinline__ float bf2f(unsigned short u) {
    return __uint_as_float((unsigned)u << 16);
}
__device__ __forceinline__ unsigned pack_bf2(float lo, float hi) {
    __hip_bfloat162 h2 = __float22bfloat162_rn(make_float2(lo, hi));
    return *reinterpret_cast<unsigned*>(&h2);   // .x low 16 bits (RNE = f2bf)
}

// Pre-bake per-lane-class (class = lane = g*16+ocl) MFMA fragments into ws.
__global__ __launch_bounds__(64) void prep_kernel(
    const float* __restrict__ w1f, const float* __restrict__ w2f,
    float* __restrict__ wsf)
{
    const int L = threadIdx.x;           // lane class 0..63
    const int ocl = L & 15, g = L >> 4;
    unsigned short* w1fr = (unsigned short*)(wsf + W1F_OFF);
#pragma unroll
    for (int e = 0; e < 8; ++e) {
        int k = g * 8 + e;
        unsigned short v0 = 0, v1 = 0;
        if (k < 27) {
            v0 = f2bf(w1f[(2 * ocl)     * 27 + k]);
            v1 = f2bf(w1f[(2 * ocl + 1) * 27 + k]);
        }
        w1fr[L * 16 + e]     = v0;
        w1fr[L * 16 + 8 + e] = v1;
    }
    char* w2fr = (char*)(wsf + W2F_OFF);
#pragma unroll
    for (int c = 0; c < 9; ++c) {
        float w[8];
#pragma unroll
        for (int e = 0; e < 8; ++e)
            w[e] = w2f[(ocl * 32 + g * 8 + e) * 9 + c];
        int lo = __builtin_amdgcn_cvt_pk_fp8_f32(w[0], w[1], 0, false);
        lo     = __builtin_amdgcn_cvt_pk_fp8_f32(w[2], w[3], lo, true);
        int hi = __builtin_amdgcn_cvt_pk_fp8_f32(w[4], w[5], 0, false);
        hi     = __builtin_amdgcn_cvt_pk_fp8_f32(w[6], w[7], hi, true);
        long v = (long)(unsigned)lo | ((long)hi << 32);
        *reinterpret_cast<long*>(w2fr + L * 72 + c * 8) = v;
    }
}

// Fused seg: one 16x16 tile per block. stage -> conv1 bf16 MFMA -> conv2 fp8
// MFMA -> conv3 epilogue + masked sums. 2 barriers per block.
__global__ __launch_bounds__(256) void seg_kernel(
    const float* __restrict__ x,
    const float* __restrict__ b1f, const float* __restrict__ b2f,
    const float* __restrict__ w3f, const float* __restrict__ b3f,
    const float* __restrict__ wsf,
    float* __restrict__ colsum, float* __restrict__ out)
{
    const int tid  = threadIdx.x;
    const int lane = tid & 63;
    const int wid  = tid >> 6;
    const int img  = blockIdx.x >> 6;        // b*64+t
    const int tile = blockIdx.x & 63;
    const int r0 = (tile >> 3) * 16, c0 = (tile & 7) * 16;
    const bool interior = (r0 >= 16 && r0 <= 96 && c0 >= 16 && c0 <= 96);

    __shared__ __align__(4)  unsigned short in_bs[1200];  // 3x20x20 bf16 halo
    __shared__ __align__(16) unsigned char h1_s[12960];   // [(y*18+x)*40+oc] fp8
    __shared__ float red[4][4];

    const int ocl = lane & 15;   // free idx
    const int g   = lane >> 4;   // k-group (8 k's each)

    // ---- fragments from ws (prep-baked; lane == class) ----
    const unsigned short* w1fr = (const unsigned short*)(wsf + W1F_OFF);
    bf16x8 c1b0 = *reinterpret_cast<const bf16x8*>(&w1fr[lane * 16]);
    bf16x8 c1b1 = *reinterpret_cast<const bf16x8*>(&w1fr[lane * 16 + 8]);
    const char* w2fr = (const char*)(wsf + W2F_OFF);
    long bfrag[9];
#pragma unroll
    for (int c = 0; c < 9; ++c)
        bfrag[c] = *reinterpret_cast<const long*>(w2fr + lane * 72 + c * 8);

    int offB[8];                 // per-lane in_bs element offsets for A gather
#pragma unroll
    for (int e = 0; e < 8; ++e) {
        int k = g * 8 + e;
        if (k < 27) {
            int ic = k / 9, r2 = k - ic * 9, ky = r2 / 3, kx = r2 - ky * 3;
            offB[e] = ic * 400 + ky * 20 + kx;
        } else offB[e] = 0;
    }
    const float b1_e = b1f[2 * ocl], b1_o = b1f[2 * ocl + 1];
    float b2v[4], w3v[4];
#pragma unroll
    for (int r = 0; r < 4; ++r) { b2v[r] = b2f[g * 4 + r]; w3v[r] = w3f[g * 4 + r]; }
    const float b3v = b3f[0];

    const float* xin = x + (size_t)img * 3 * 16384;

    // ---- stage 20x20x3 halo as bf16: thread t<240 owns 5 consecutive
    //      elements of LDS row (t>>2); col = (t&3)*5. ----
    if (tid < 240) {
        int row = tid >> 2;                  // 0..59 = ic*20 + r
        int col = (tid & 3) * 5;             // 0,5,10,15
        int ic  = (row * 13) >> 8;           // row/20 for row<60
        int r   = row - ic * 20;
        int gr  = r0 - 2 + r;
        int gc0 = c0 - 2 + col;
        float v0, v1, v2, v3, v4;
        if (interior || ((unsigned)gr < 128u && gc0 >= 0 && gc0 + 4 < 128)) {
            const float* src = xin + ic * 16384 + gr * 128 + gc0;
            f32x4 q = *reinterpret_cast<const f32x4*>(src);
            v0 = q[0]; v1 = q[1]; v2 = q[2]; v3 = q[3]; v4 = src[4];
        } else {
            const float* srow = xin + ic * 16384 + gr * 128;
            bool rok = (unsigned)gr < 128u;
            v0 = (rok && (unsigned)(gc0 + 0) < 128u) ? srow[gc0 + 0] : 0.f;
            v1 = (rok && (unsigned)(gc0 + 1) < 128u) ? srow[gc0 + 1] : 0.f;
            v2 = (rok && (unsigned)(gc0 + 2) < 128u) ? srow[gc0 + 2] : 0.f;
            v3 = (rok && (unsigned)(gc0 + 3) < 128u) ? srow[gc0 + 3] : 0.f;
            v4 = (rok && (unsigned)(gc0 + 4) < 128u) ? srow[gc0 + 4] : 0.f;
        }
        unsigned short* dst = &in_bs[row * 20 + col];
        if ((col & 1) == 0) {
            *reinterpret_cast<unsigned*>(dst)     = pack_bf2(v0, v1);
            *reinterpret_cast<unsigned*>(dst + 2) = pack_bf2(v2, v3);
            dst[4] = f2bf(v4);
        } else {
            dst[0] = f2bf(v0);
            *reinterpret_cast<unsigned*>(dst + 1) = pack_bf2(v1, v2);
            *reinterpret_cast<unsigned*>(dst + 3) = pack_bf2(v3, v4);
        }
    }
    __syncthreads();

    // ---- conv1 MFMA: groups grp = wid + gi*4; gi<5 unchecked, gi=5 checked
#pragma unroll
    for (int gi = 0; gi < 6; ++gi) {
        const int grp = wid + gi * 4;
        if (gi == 5 && grp != 20) break;      // only wid==0 runs grp 20
        int pos = grp * 16 + ocl;             // A row
        int hy = pos / 18, hx = pos - hy * 18;
        int base = hy * 20 + hx;
        base = base > 357 ? 357 : base;       // clamp tail-group lanes
        bf16x8 afrag;
#pragma unroll
        for (int e = 0; e < 8; ++e)
            afrag[e] = (short)in_bs[base + offB[e]];
        f32x4 d0 = {0.f, 0.f, 0.f, 0.f}, d1 = {0.f, 0.f, 0.f, 0.f};
        d0 = __builtin_amdgcn_mfma_f32_16x16x32_bf16(afrag, c1b0, d0, 0, 0, 0);
        d1 = __builtin_amdgcn_mfma_f32_16x16x32_bf16(afrag, c1b1, d1, 0, 0, 0);
        int p0 = grp * 16 + g * 4;
        if (interior) {
#pragma unroll
            for (int r = 0; r < 4; ++r) {
                int p2 = p0 + r;
                if (gi < 5 || p2 < 324) {
                    int pk = __builtin_amdgcn_cvt_pk_fp8_f32(
                        fmaxf(d0[r] + b1_e, 0.f), fmaxf(d1[r] + b1_o, 0.f), 0, false);
                    *reinterpret_cast<unsigned short*>(&h1_s[p2 * 40 + 2 * ocl]) =
                        (unsigned short)pk;
                }
            }
        } else {
            int hy2 = p0 / 18, hx2 = p0 - hy2 * 18;
#pragma unroll
            for (int r = 0; r < 4; ++r) {
                int p2 = p0 + r;
                if (gi < 5 || p2 < 324) {
                    bool valid = ((unsigned)(r0 - 1 + hy2) < 128u) &&
                                 ((unsigned)(c0 - 1 + hx2) < 128u);
                    float he = valid ? fmaxf(d0[r] + b1_e, 0.f) : 0.f;
                    float ho = valid ? fmaxf(d1[r] + b1_o, 0.f) : 0.f;
                    int pk = __builtin_amdgcn_cvt_pk_fp8_f32(he, ho, 0, false);
                    *reinterpret_cast<unsigned short*>(&h1_s[p2 * 40 + 2 * ocl]) =
                        (unsigned short)pk;
                }
                ++hx2;
                if (hx2 == 18) { hx2 = 0; ++hy2; }
            }
        }
    }
    __syncthreads();

    // ---- conv2 FP8 MFMA (A=w2, B=h1; row-reuse, per-q order fixed) ----
    const unsigned char* hb = &h1_s[((wid * 4) * 18 + ocl) * 40 + g * 8];
    f32x4 acc4[4];
#pragma unroll
    for (int q = 0; q < 4; ++q) acc4[q] = (f32x4){0.f, 0.f, 0.f, 0.f};
#pragma unroll
    for (int rp = 0; rp < 6; ++rp) {
        long fr0 = *reinterpret_cast<const long*>(hb + (rp * 18 + 0) * 40);
        long fr1 = *reinterpret_cast<const long*>(hb + (rp * 18 + 1) * 40);
        long fr2 = *reinterpret_cast<const long*>(hb + (rp * 18 + 2) * 40);
#pragma unroll
        for (int ky = 0; ky < 3; ++ky) {
            const int q = rp - ky;
            if (q >= 0 && q < 4) {
                acc4[q] = __builtin_amdgcn_mfma_f32_16x16x32_fp8_fp8(
                    bfrag[ky * 3 + 0], fr0, acc4[q], 0, 0, 0);
                acc4[q] = __builtin_amdgcn_mfma_f32_16x16x32_fp8_fp8(
                    bfrag[ky * 3 + 1], fr1, acc4[q], 0, 0, 0);
                acc4[q] = __builtin_amdgcn_mfma_f32_16x16x32_fp8_fp8(
                    bfrag[ky * 3 + 2], fr2, acc4[q], 0, 0, 0);
            }
        }
    }
    // conv3: per q: 4 in-lane FMA + 2 shfl (all lanes get column sum for their
    // ocl). Lane-group g keeps q==g -> sigmoid/store/masked-sum on ALL lanes.
    float mypart = 0.f;
#pragma unroll
    for (int q = 0; q < 4; ++q) {
        float part3 = 0.f;
#pragma unroll
        for (int r = 0; r < 4; ++r)
            part3 = fmaf(fmaxf(acc4[q][r] + b2v[r], 0.f), w3v[r], part3);
        part3 += __shfl_xor(part3, 16);
        part3 += __shfl_xor(part3, 32);
        if (q == g) mypart = part3;
    }
    float s0, s1, s2, sm;
    {
        const int s = wid * 4 + g;           // my output row
        const int xw = ocl;                  // my output column
        float e = __expf(-(mypart + b3v));
        float msk = __builtin_amdgcn_rcpf(1.f + e);
        out[776 + (size_t)img * 16384 + (size_t)(r0 + s) * 128 + (c0 + xw)] = msk;
        float f0  = bf2f(in_bs[      (s + 2) * 20 + (xw + 2)]);
        float f1v = bf2f(in_bs[400 + (s + 2) * 20 + (xw + 2)]);
        float f2v = bf2f(in_bs[800 + (s + 2) * 20 + (xw + 2)]);
        s0 = msk * f0;
        s1 = msk * f1v;
        s2 = msk * f2v;
        sm = msk;
    }

    // ---- block reduction of the 4 sums ----
#pragma unroll
    for (int off = 32; off > 0; off >>= 1) {
        s0 += __shfl_down(s0, off);
        s1 += __shfl_down(s1, off);
        s2 += __shfl_down(s2, off);
        sm += __shfl_down(sm, off);
    }
    if (lane == 0) { red[wid][0] = s0; red[wid][1] = s1; red[wid][2] = s2; red[wid][3] = sm; }
    __syncthreads();
    if (tid < 4) {
        float s = red[0][tid] + red[1][tid] + red[2][tid] + red[3][tid];
        colsum[(size_t)blockIdx.x * 4 + tid] = s;   // [img*64+tile][4]
    }
}

// Tail: 1024 threads; ta2/ta3 vectorized (b128 + lane-shfl conv halo).
__global__ __launch_bounds__(1024) void tail_kernel(
    const float* __restrict__ colsum,
    const float* __restrict__ cw1, const float* __restrict__ cb1,
    const float* __restrict__ cw2, const float* __restrict__ cb2,
    const float* __restrict__ cw3, const float* __restrict__ cb3,
    const float* __restrict__ tw1, const float* __restrict__ tb1,
    const float* __restrict__ tw2, const float* __restrict__ tb2,
    const float* __restrict__ tw3, const float* __restrict__ tb3,
    const float* __restrict__ fw1, const float* __restrict__ fb1,
    const float* __restrict__ fw2, const float* __restrict__ fb2,
    const float* __restrict__ fw3, const float* __restrict__ fb3,
    float* __restrict__ out)
{
    const int b = blockIdx.x, tid = threadIdx.x;
    __shared__ float tmp[64][4];
    __shared__ float cs_s[3 * 64];
    __shared__ float e3s[3 * 64];
    __shared__ __align__(16) float f1[32 * 64];
    __shared__ __align__(16) float f2[64 * 64];
    __shared__ __align__(16) float tf[32 * 64];
    __shared__ float pooled[32], g1[64], g2[32], sca[8];

    if (tid < 256) {
        int t = tid >> 2, slot = tid & 3;
        const float* pp = colsum + (size_t)((b * 64 + t) * 64) * 4 + slot;
        float s = 0.f;
#pragma unroll
        for (int tl = 0; tl < 64; ++tl) s += pp[tl * 4];
        tmp[t][slot] = s;
    }
    __syncthreads();
    if (tid < 192) {
        int c = tid >> 6, t = tid & 63;
        float v = tmp[t][c] / (tmp[t][3] + 1e-8f);
        cs_s[tid] = v;
        out[8 + (b * 64 + t) * 3 + c] = v;
    }
    __syncthreads();

    if (tid < 64) {
        int t = tid;
        float c0v = cs_s[t], c1v = cs_s[64 + t], c2v = cs_s[128 + t];
        float e1[16];
#pragma unroll
        for (int o = 0; o < 16; ++o)
            e1[o] = fmaxf(cb1[o] + cw1[o * 3 + 0] * c0v + cw1[o * 3 + 1] * c1v
                                 + cw1[o * 3 + 2] * c2v, 0.f);
        float e2[8];
#pragma unroll
        for (int o = 0; o < 8; ++o) {
            float a = cb2[o];
#pragma unroll
            for (int i2 = 0; i2 < 16; ++i2) a += cw2[o * 16 + i2] * e1[i2];
            e2[o] = fmaxf(a, 0.f);
        }
#pragma unroll
        for (int o = 0; o < 3; ++o) {
            float a = cb3[o];
#pragma unroll
            for (int i2 = 0; i2 < 8; ++i2) a += cw3[o * 8 + i2] * e2[i2];
            e3s[o * 64 + t] = a;   // no relu on last ct conv
        }
    }
    __syncthreads();

    // ta1: 3->32 k3 p1
    {
        int o = tid >> 6, t = tid & 63;
#pragma unroll
        for (int h = 0; h < 2; ++h) {
            int oo = o + 16 * h;
            float a = tb1[oo];
#pragma unroll
            for (int ic = 0; ic < 3; ++ic)
#pragma unroll
                for (int k = 0; k < 3; ++k) {
                    int ttk = t + k - 1;
                    if ((unsigned)ttk < 64u)
                        a += e3s[ic * 64 + ttk] * tw1[(oo * 3 + ic) * 3 + k];
                }
            f1[oo * 64 + t] = fmaxf(a, 0.f);
        }
    }
    __syncthreads();

    // ta2: 32->64 k3 p1 — thread (oo=tid>>4, t4=tid&15) computes t=4t4..4t4+3
    {
        int oo = tid >> 4, t4 = tid & 15;
        float a0 = tb2[oo], a1 = a0, a2 = a0, a3 = a0;
        for (int ic = 0; ic < 32; ++ic) {
            f32x4 c = *reinterpret_cast<const f32x4*>(&f1[ic * 64 + t4 * 4]);
            float pm = __shfl_up(c[3], 1);
            float pp = __shfl_down(c[0], 1);
            if (t4 == 0)  pm = 0.f;          // t-1 < 0 pad
            if (t4 == 15) pp = 0.f;          // t+1 > 63 pad
            const float* wp = tw2 + (oo * 32 + ic) * 3;
            float w0 = wp[0], w1 = wp[1], w2 = wp[2];
            a0 = fmaf(w0, pm,   fmaf(w1, c[0], fmaf(w2, c[1], a0)));
            a1 = fmaf(w0, c[0], fmaf(w1, c[1], fmaf(w2, c[2], a1)));
            a2 = fmaf(w0, c[1], fmaf(w1, c[2], fmaf(w2, c[3], a2)));
            a3 = fmaf(w0, c[2], fmaf(w1, c[3], fmaf(w2, pp,   a3)));
        }
        f32x4 r = {fmaxf(a0, 0.f), fmaxf(a1, 0.f), fmaxf(a2, 0.f), fmaxf(a3, 0.f)};
        *reinterpret_cast<f32x4*>(&f2[oo * 64 + t4 * 4]) = r;
    }
    __syncthreads();

    // ta3: 64->32 k3 p1 (+ temporal_features out), threads 0..511
    if (tid < 512) {
        int oo = tid >> 4, t4 = tid & 15;
        float a0 = tb3[oo], a1 = a0, a2 = a0, a3 = a0;
        for (int ic = 0; ic < 64; ++ic) {
            f32x4 c = *reinterpret_cast<const f32x4*>(&f2[ic * 64 + t4 * 4]);
            float pm = __shfl_up(c[3], 1);
            float pp = __shfl_down(c[0], 1);
            if (t4 == 0)  pm = 0.f;
            if (t4 == 15) pp = 0.f;
            const float* wp = tw3 + (oo * 64 + ic) * 3;
            float w0 = wp[0], w1 = wp[1], w2 = wp[2];
            a0 = fmaf(w0, pm,   fmaf(w1, c[0], fmaf(w2, c[1], a0)));
            a1 = fmaf(w0, c[0], fmaf(w1, c[1], fmaf(w2, c[2], a1)));
            a2 = fmaf(w0, c[1], fmaf(w1, c[2], fmaf(w2, c[3], a2)));
            a3 = fmaf(w0, c[2], fmaf(w1, c[3], fmaf(w2, pp,   a3)));
        }
        f32x4 r = {fmaxf(a0, 0.f), fmaxf(a1, 0.f), fmaxf(a2, 0.f), fmaxf(a3, 0.f)};
        *reinterpret_cast<f32x4*>(&tf[oo * 64 + t4 * 4]) = r;
        *reinterpret_cast<f32x4*>(&out[TF_OFF + (b * 32 + oo) * 64 + t4 * 4]) = r;
    }
    __syncthreads();

    if (tid < 32) {
        float s = 0.f;
#pragma unroll
        for (int t4 = 0; t4 < 16; ++t4) {
            f32x4 c = *reinterpret_cast<const f32x4*>(&tf[tid * 64 + t4 * 4]);
            s += c[0] + c[1] + c[2] + c[3];
        }
        pooled[tid] = s * (1.f / 64.f);
    }
    __syncthreads();

    if (tid < 64) {
        float a = fb1[tid];
#pragma unroll
        for (int i2 = 0; i2 < 32; ++i2) a += pooled[i2] * fw1[tid * 32 + i2];
        g1[tid] = fmaxf(a, 0.f);
    }
    __syncthreads();
    if (tid < 32) {
        float a = fb2[tid];
        for (int i2 = 0; i2 < 64; ++i2) a += g1[i2] * fw2[tid * 64 + i2];
        g2[tid] = fmaxf(a, 0.f);
    }
    __syncthreads();
    if (tid == 0) {
        float a = fb3[0];
        for (int i2 = 0; i2 < 32; ++i2) a += g2[i2] * fw3[i2];
        float flow = 1.f / (1.f + expf(-a));
        sca[0] = flow;
        out[b] = flow;
    }
    if (tid >= 4 && tid < 7) {
        int c = tid - 4;
        float mu = 0.f;
        for (int t = 0; t < 64; ++t) mu += cs_s[c * 64 + t];
        mu *= (1.f / 64.f);
        float v = 0.f;
        for (int t = 0; t < 64; ++t) { float d = cs_s[c * 64 + t] - mu; v += d * d; }
        sca[1 + c] = sqrtf(v / 63.f);
    }
    __syncthreads();
    if (tid == 0) {
        float s0 = sca[1], s1 = sca[2], s2 = sca[3];
        float mu = (s0 + s1 + s2) * (1.f / 3.f);
        float var = ((s0 - mu) * (s0 - mu) + (s1 - mu) * (s1 - mu) + (s2 - mu) * (s2 - mu)) * 0.5f;
        float sy = 1.f / (1.f + expf(var));     // sigmoid(-var)
        out[4 + b] = sy;
        out[NAT_OFF + b] = (sca[0] + sy) * 0.5f;
    }
}

extern "C" void kernel_launch(void* const* d_in, const int* in_sizes, int n_in,
                              void* d_out, int out_size, void* d_ws, size_t ws_size,
                              hipStream_t stream)
{
    float* wsf = (float*)d_ws;
    float* out = (float*)d_out;

    prep_kernel<<<1, 64, 0, stream>>>(
        (const float*)d_in[1], (const float*)d_in[3], wsf);

    seg_kernel<<<dim3(16384), 256, 0, stream>>>((const float*)d_in[0],
        (const float*)d_in[2], (const float*)d_in[4],
        (const float*)d_in[5], (const float*)d_in[6],
        wsf, wsf, out);

    tail_kernel<<<dim3(4), 1024, 0, stream>>>(wsf,
        (const float*)d_in[7],  (const float*)d_in[8],
        (const float*)d_in[9],  (const float*)d_in[10],
        (const float*)d_in[11], (const float*)d_in[12],
        (const float*)d_in[13], (const float*)d_in[14],
        (const float*)d_in[15], (const float*)d_in[16],
        (const float*)d_in[17], (const float*)d_in[18],
        (const float*)d_in[19], (const float*)d_in[20],
        (const float*)d_in[21], (const float*)d_in[22],
        (const float*)d_in[23], (const float*)d_in[24],
        out);
}